// Round 8
// baseline (426.142 us; speedup 1.0000x reference)
//
#include <hip/hip_runtime.h>
#include <hip/hip_bf16.h>
#include <hip/hip_fp16.h>

#define DD 128
#define BN_EPS 1e-5f

typedef __attribute__((ext_vector_type(8))) short bf16x8;
typedef __attribute__((ext_vector_type(4))) float f32x4;

static __device__ __forceinline__ unsigned short f2bf(float f) {
    __hip_bfloat16 h = __float2bfloat16(f);   // RNE
    return *reinterpret_cast<unsigned short*>(&h);
}
static __device__ __forceinline__ float bf2f(unsigned short u) {
    return __uint_as_float(((unsigned)u) << 16);
}
static __device__ __forceinline__ unsigned pack_rec(int col, float val) {
    __half h = __float2half(val);
    unsigned hb = *reinterpret_cast<unsigned short*>(&h);
    return (unsigned)col | (hb << 16);
}
static __device__ __forceinline__ float rec_val(unsigned rec) {
    unsigned short hb = (unsigned short)(rec >> 16);
    __half h = *reinterpret_cast<__half*>(&hb);
    return __half2float(h);
}

// ---------------------------------------------------------------- zero
__global__ __launch_bounds__(256) void zero_int_kernel(int* __restrict__ p, int n) {
    int i = blockIdx.x * 256 + threadIdx.x;
    if (i < n) p[i] = 0;
}

// ---------------------------------------------------------------- prep weights + histogram (fused)
// blocks 0-3: transpose+convert weight matrices; blocks 4+: row histogram
__global__ __launch_bounds__(256) void prep_hist(
    const float* __restrict__ W, const float* __restrict__ Wself,
    unsigned short* __restrict__ Wt4,
    const int* __restrict__ arow, int* __restrict__ counts, int E)
{
    if (blockIdx.x < 4) {
        int mat = blockIdx.x;        // 0:L0 W, 1:L0 Wself, 2:L1 W, 3:L1 Wself
        int layer = mat >> 1;
        const float* src = (mat & 1) ? (Wself + layer * 16384) : (W + layer * 16384);
        unsigned short* dst = Wt4 + (size_t)mat * 16384;
        for (int i = threadIdx.x; i < 16384; i += 256) {
            int n = i >> 7, k = i & 127;
            dst[i] = f2bf(src[k * 128 + n]);
        }
    } else {
        int e = (blockIdx.x - 4) * 256 + threadIdx.x;
        if (e < E) atomicAdd(&counts[arow[e]], 1);
    }
}

// ---------------------------------------------------------------- scan (3 phases)
__global__ __launch_bounds__(256) void block_sums(
    const int* __restrict__ counts, int* __restrict__ bsums, int n)
{
    int base = blockIdx.x * 1024 + threadIdx.x * 4;
    int s = 0;
    #pragma unroll
    for (int j = 0; j < 4; j++) { int i = base + j; if (i < n) s += counts[i]; }
    #pragma unroll
    for (int off = 1; off < 64; off <<= 1) s += __shfl_xor(s, off);
    __shared__ int ws[4];
    int lane = threadIdx.x & 63, w = threadIdx.x >> 6;
    if (lane == 0) ws[w] = s;
    __syncthreads();
    if (threadIdx.x == 0) bsums[blockIdx.x] = ws[0] + ws[1] + ws[2] + ws[3];
}

__global__ __launch_bounds__(1024) void scan_bsums(
    int* __restrict__ bsums, int nb, int* __restrict__ offs, int n)
{
    __shared__ int sh[1024];
    int tid = threadIdx.x;
    int v = (tid < nb) ? bsums[tid] : 0;
    sh[tid] = v;
    __syncthreads();
    for (int off = 1; off < 1024; off <<= 1) {
        int t = (tid >= off) ? sh[tid - off] : 0;
        __syncthreads();
        sh[tid] += t;
        __syncthreads();
    }
    if (tid < nb) bsums[tid] = sh[tid] - v;   // exclusive
    if (tid == 0) offs[n] = sh[1023];         // grand total
}

__global__ __launch_bounds__(256) void scan_final(
    const int* __restrict__ counts, const int* __restrict__ bsums,
    int* __restrict__ offs, int* __restrict__ cursor, int n)
{
    int tid  = threadIdx.x;
    int base = blockIdx.x * 1024 + tid * 4;
    int c[4]; int s = 0;
    #pragma unroll
    for (int j = 0; j < 4; j++) { int i = base + j; c[j] = (i < n) ? counts[i] : 0; s += c[j]; }
    int lane = tid & 63, w = tid >> 6;
    int inc = s;
    #pragma unroll
    for (int off = 1; off < 64; off <<= 1) {
        int t = __shfl_up(inc, off);
        if (lane >= off) inc += t;
    }
    __shared__ int ws[4];
    if (lane == 63) ws[w] = inc;
    __syncthreads();
    int woff = 0;
    for (int k = 0; k < w; k++) woff += ws[k];
    int excl = bsums[blockIdx.x] + woff + inc - s;
    #pragma unroll
    for (int j = 0; j < 4; j++) {
        int i = base + j;
        if (i < n) { offs[i] = excl; cursor[i] = excl; }
        excl += c[j];
    }
}

// ---------------------------------------------------------------- XCD-partitioned scatter
// grid = 256 blocks (1/CU, co-resident => blockIdx%8 ~ XCD); 32 slices x 8 partitions
__global__ __launch_bounds__(1024) void scatter_part(
    const int* __restrict__ arow, const int* __restrict__ acol,
    const float* __restrict__ aval, int* __restrict__ cursor,
    unsigned* __restrict__ packed, int E, int rpp)
{
    const int p     = blockIdx.x & 7;
    const int slice = blockIdx.x >> 3;
    const int nsl   = gridDim.x >> 3;
    const int e0    = (int)((long long)E * slice / nsl);
    const int e1    = (int)((long long)E * (slice + 1) / nsl);
    for (int e = e0 + threadIdx.x; e < e1; e += 1024) {
        int r = arow[e];
        if (r / rpp == p) {
            int pos = atomicAdd(&cursor[r], 1);
            packed[pos] = pack_rec(acol[e], aval[e]);
        }
    }
}

// ---------------------------------------------------------------- MFMA GEMM (+inline BN/ReLU on A)
// A fp32 [N][128]. useBN: a = relu(a*sc+sh) (layer-1 input path). Converts to bf16 in-register.
// support(bf16) = A' @ W ; outb(f32) = A' @ W_self + b
__global__ __launch_bounds__(256) void gemm_mfma(
    const float* __restrict__ A,
    const unsigned short* __restrict__ Wt, const unsigned short* __restrict__ Wst,
    const float* __restrict__ bias,
    const float* __restrict__ stats, const float* __restrict__ gamma,
    const float* __restrict__ beta, float invN, int useBN,
    unsigned short* __restrict__ support, float* __restrict__ outb, int N)
{
    __shared__ float ssc[128], ssh[128];
    if (useBN) {
        if (threadIdx.x < 128) {
            int c = threadIdx.x;
            float mean = stats[c] * invN;
            float var  = stats[128 + c] * invN - mean * mean;
            float sc   = gamma[c] * rsqrtf(var + BN_EPS);
            ssc[c] = sc;
            ssh[c] = beta[c] - mean * sc;
        }
        __syncthreads();
    }

    const int wave = threadIdx.x >> 6;
    const int lane = threadIdx.x & 63;
    const int m    = lane & 15;
    const int quad = lane >> 4;
    const int row0 = blockIdx.x * 64 + wave * 16;

    int arow = row0 + m; if (arow > N - 1) arow = N - 1;
    const float* Ar = A + (size_t)arow * 128;
    bf16x8 af[4];
    #pragma unroll
    for (int ch = 0; ch < 4; ch++) {
        int k0 = ch * 32 + quad * 8;
        float4 u = *(const float4*)&Ar[k0];
        float4 v = *(const float4*)&Ar[k0 + 4];
        float vals[8] = {u.x, u.y, u.z, u.w, v.x, v.y, v.z, v.w};
        #pragma unroll
        for (int j = 0; j < 8; j++) {
            float val = vals[j];
            if (useBN) {
                val = val * ssc[k0 + j] + ssh[k0 + j];
                val = val > 0.f ? val : 0.f;
            }
            af[ch][j] = (short)f2bf(val);
        }
    }

    f32x4 acc1[8], acc2[8];
    #pragma unroll
    for (int nt = 0; nt < 8; nt++) {
        acc1[nt] = (f32x4)(0.f);
        acc2[nt] = (f32x4)(0.f);
    }

    #pragma unroll
    for (int nt = 0; nt < 8; nt++) {
        const bf16x8* B1 = (const bf16x8*)(Wt  + ((size_t)(nt * 16 + m)) * 128 + quad * 8);
        const bf16x8* B2 = (const bf16x8*)(Wst + ((size_t)(nt * 16 + m)) * 128 + quad * 8);
        acc1[nt] = __builtin_amdgcn_mfma_f32_16x16x32_bf16(af[0], B1[0],  acc1[nt], 0, 0, 0);
        acc2[nt] = __builtin_amdgcn_mfma_f32_16x16x32_bf16(af[0], B2[0],  acc2[nt], 0, 0, 0);
        acc1[nt] = __builtin_amdgcn_mfma_f32_16x16x32_bf16(af[1], B1[4],  acc1[nt], 0, 0, 0);
        acc2[nt] = __builtin_amdgcn_mfma_f32_16x16x32_bf16(af[1], B2[4],  acc2[nt], 0, 0, 0);
        acc1[nt] = __builtin_amdgcn_mfma_f32_16x16x32_bf16(af[2], B1[8],  acc1[nt], 0, 0, 0);
        acc2[nt] = __builtin_amdgcn_mfma_f32_16x16x32_bf16(af[2], B2[8],  acc2[nt], 0, 0, 0);
        acc1[nt] = __builtin_amdgcn_mfma_f32_16x16x32_bf16(af[3], B1[12], acc1[nt], 0, 0, 0);
        acc2[nt] = __builtin_amdgcn_mfma_f32_16x16x32_bf16(af[3], B2[12], acc2[nt], 0, 0, 0);
    }

    float bv[8];
    #pragma unroll
    for (int nt = 0; nt < 8; nt++) bv[nt] = bias[nt * 16 + m];

    // C/D layout: col = lane&15, row = quad*4 + reg
    #pragma unroll
    for (int r = 0; r < 4; r++) {
        int orow = row0 + quad * 4 + r;
        if (orow < N) {
            size_t base = (size_t)orow * 128 + m;
            #pragma unroll
            for (int nt = 0; nt < 8; nt++) {
                support[base + nt * 16] = f2bf(acc1[nt][r]);
                outb[base + nt * 16]    = acc2[nt][r] + bv[nt];
            }
        }
    }
}

// ---------------------------------------------------------------- SpMM + fused BN stats
// grid-stride over row groups of 8; per-thread register stats, one atomic/column/block
__global__ __launch_bounds__(256) void spmm_stats(
    const int* __restrict__ offs, const unsigned* __restrict__ packed,
    const unsigned short* __restrict__ sup, float* __restrict__ outb,
    float* __restrict__ stats, int ngroups, int N)
{
    const int r    = threadIdx.x & 31;   // column quad
    const int slot = threadIdx.x >> 5;   // row within group
    float s4[4] = {0.f, 0.f, 0.f, 0.f};
    float q4[4] = {0.f, 0.f, 0.f, 0.f};

    for (int g = blockIdx.x; g < ngroups; g += gridDim.x) {
        int row = g * 8 + slot;
        if (row >= N) continue;
        int beg = offs[row], end = offs[row + 1];
        float4 acc = make_float4(0.f, 0.f, 0.f, 0.f);
        int e = beg;
        for (; e + 8 <= end; e += 8) {
            unsigned pr[8];
            #pragma unroll
            for (int j = 0; j < 8; j++) pr[j] = packed[e + j];
            ushort4 sv[8];
            #pragma unroll
            for (int j = 0; j < 8; j++)
                sv[j] = *(const ushort4*)&sup[((size_t)(pr[j] & 0xFFFFu) << 7) + r * 4];
            #pragma unroll
            for (int j = 0; j < 8; j++) {
                float v = rec_val(pr[j]);
                acc.x += v * bf2f(sv[j].x); acc.y += v * bf2f(sv[j].y);
                acc.z += v * bf2f(sv[j].z); acc.w += v * bf2f(sv[j].w);
            }
        }
        for (; e < end; e++) {
            unsigned pr = packed[e];
            ushort4 sv = *(const ushort4*)&sup[((size_t)(pr & 0xFFFFu) << 7) + r * 4];
            float v = rec_val(pr);
            acc.x += v * bf2f(sv.x); acc.y += v * bf2f(sv.y);
            acc.z += v * bf2f(sv.z); acc.w += v * bf2f(sv.w);
        }
        float4* op = (float4*)&outb[((size_t)row << 7) + r * 4];
        float4 o = *op;
        o.x += acc.x; o.y += acc.y; o.z += acc.z; o.w += acc.w;
        *op = o;
        s4[0] += o.x; s4[1] += o.y; s4[2] += o.z; s4[3] += o.w;
        q4[0] += o.x * o.x; q4[1] += o.y * o.y; q4[2] += o.z * o.z; q4[3] += o.w * o.w;
    }

    __shared__ float red[8][128];
    #pragma unroll
    for (int j = 0; j < 4; j++) red[slot][r * 4 + j] = s4[j];
    __syncthreads();
    float ts = 0.f;
    if (threadIdx.x < 128) {
        #pragma unroll
        for (int j = 0; j < 8; j++) ts += red[j][threadIdx.x];
    }
    __syncthreads();
    #pragma unroll
    for (int j = 0; j < 4; j++) red[slot][r * 4 + j] = q4[j];
    __syncthreads();
    if (threadIdx.x < 128) {
        float tq = 0.f;
        #pragma unroll
        for (int j = 0; j < 8; j++) tq += red[j][threadIdx.x];
        atomicAdd(&stats[threadIdx.x], ts);
        atomicAdd(&stats[128 + threadIdx.x], tq);
    }
}

// ---------------------------------------------------------------- final BN + residual + score
// node_emb = relu(bn(outb)) + x ; s1=emb·Wc[0:128], s2=emb·Wc[128:256]
__global__ __launch_bounds__(256) void score_kernel(
    const float* __restrict__ outb, const float* __restrict__ stats,
    const float* __restrict__ gamma, const float* __restrict__ beta,
    const float* __restrict__ x, const float* __restrict__ Wc,
    float* __restrict__ s1, float* __restrict__ s2, float invN, int N)
{
    int idx = blockIdx.x * 256 + threadIdx.x;
    if (idx >= N * 32) return;
    int c4 = (idx & 31) * 4;
    float4 o = *(const float4*)&outb[(size_t)idx * 4];
    float res[4];
    const float* op = &o.x;
    #pragma unroll
    for (int j = 0; j < 4; j++) {
        int c = c4 + j;
        float mean = stats[c] * invN;
        float var  = stats[128 + c] * invN - mean * mean;
        float sc   = gamma[c] * rsqrtf(var + BN_EPS);
        float sh   = beta[c] - mean * sc;
        float v    = op[j] * sc + sh;
        res[j] = v > 0.f ? v : 0.f;
    }
    float4 xv = *(const float4*)&x[(size_t)idx * 4];
    res[0] += xv.x; res[1] += xv.y; res[2] += xv.z; res[3] += xv.w;
    float4 w1 = *(const float4*)&Wc[c4];
    float4 w2 = *(const float4*)&Wc[128 + c4];
    float a1 = res[0] * w1.x + res[1] * w1.y + res[2] * w1.z + res[3] * w1.w;
    float a2 = res[0] * w2.x + res[1] * w2.y + res[2] * w2.z + res[3] * w2.w;
    #pragma unroll
    for (int off = 1; off < 32; off <<= 1) {
        a1 += __shfl_xor(a1, off);
        a2 += __shfl_xor(a2, off);
    }
    if ((idx & 31) == 0) {
        int row = idx >> 5;
        s1[row] = a1;
        s2[row] = a2;
    }
}

// ---------------------------------------------------------------- edge predictor (scalar)
__global__ __launch_bounds__(256) void edge_pred_scalar(
    const float* __restrict__ s1, const float* __restrict__ s2,
    const int* __restrict__ ei, const float* __restrict__ bc,
    float* __restrict__ outp, int Ep)
{
    int e = blockIdx.x * 256 + threadIdx.x;
    if (e >= Ep) return;
    float v = s1[ei[e]] + s2[ei[Ep + e]] + bc[0];
    outp[e] = 1.f / (1.f + expf(-v));
}

// ---------------------------------------------------------------- launch
extern "C" void kernel_launch(void* const* d_in, const int* in_sizes, int n_in,
                              void* d_out, int out_size, void* d_ws, size_t ws_size,
                              hipStream_t stream) {
    const float* x        = (const float*)d_in[0];
    const int*   adj_row  = (const int*)  d_in[1];
    const int*   adj_col  = (const int*)  d_in[2];
    const float* adj_val  = (const float*)d_in[3];
    const int*   ei       = (const int*)  d_in[4];
    const float* W        = (const float*)d_in[5];
    const float* W_self   = (const float*)d_in[6];
    const float* b        = (const float*)d_in[7];
    const float* gamma    = (const float*)d_in[8];
    const float* beta     = (const float*)d_in[9];
    const float* Wc       = (const float*)d_in[10];
    const float* bc       = (const float*)d_in[11];
    float* outp = (float*)d_out;

    const int N  = in_sizes[0] / DD;    // 50000
    const int E  = in_sizes[1];         // 800000
    const int Ep = in_sizes[4] / 2;     // 500000
    const float invN = 1.f / (float)N;

    size_t nd = (size_t)N * DD;
    char* p = (char*)d_ws;
    unsigned short* support16 = (unsigned short*)p; p += nd * 2;
    float*          outbA     = (float*)p;          p += nd * 4;
    float*          outbB     = (float*)p;          p += nd * 4;
    unsigned short* Wt4       = (unsigned short*)p; p += 4 * 16384 * 2;
    float*          stats     = (float*)p;          p += 512 * 4;   // contiguous with counts
    int*            counts    = (int*)p;            p += (size_t)N * 4;
    int*            offs      = (int*)p;            p += (size_t)(N + 2) * 4;
    int*            cursor    = (int*)p;            p += (size_t)N * 4;
    unsigned*       packed    = (unsigned*)p;       p += (size_t)E * 4;
    int*            bsums     = (int*)p;            p += 1024 * 4;
    float*          s1        = (float*)p;          p += (size_t)N * 4;
    float*          s2        = (float*)p;

    const int nb  = (N + 1023) / 1024;
    const int rpp = (N + 7) / 8;
    const int ngroups = (N + 7) / 8;

    // zero stats (512 fp32 == int 0) + counts (contiguous)
    zero_int_kernel<<<(512 + N + 255) / 256, 256, 0, stream>>>((int*)stats, 512 + N);
    // weight transpose/convert + row histogram
    prep_hist<<<4 + (E + 255) / 256, 256, 0, stream>>>(W, W_self, Wt4, adj_row, counts, E);
    // scan -> offs, cursor
    block_sums<<<nb, 256, 0, stream>>>(counts, bsums, N);
    scan_bsums<<<1, 1024, 0, stream>>>(bsums, nb, offs, N);
    scan_final<<<nb, 256, 0, stream>>>(counts, bsums, offs, cursor, N);
    // XCD-affine scatter into packed CSR records
    scatter_part<<<256, 1024, 0, stream>>>(adj_row, adj_col, adj_val, cursor, packed, E, rpp);

    const int gemm_grid  = (N + 63) / 64;
    const int score_grid = (N * 32 + 255) / 256;

    // ---- layer 0 ----
    gemm_mfma<<<gemm_grid, 256, 0, stream>>>(
        x, Wt4 + 0 * 16384, Wt4 + 1 * 16384, b,
        nullptr, nullptr, nullptr, invN, 0,
        support16, outbA, N);
    spmm_stats<<<2048, 256, 0, stream>>>(offs, packed, support16, outbA, stats, ngroups, N);

    // ---- layer 1 (BN of layer-0 fused into A staging) ----
    gemm_mfma<<<gemm_grid, 256, 0, stream>>>(
        outbA, Wt4 + 2 * 16384, Wt4 + 3 * 16384, b + DD,
        stats, gamma, beta, invN, 1,
        support16, outbB, N);
    spmm_stats<<<2048, 256, 0, stream>>>(offs, packed, support16, outbB, stats + 256, ngroups, N);

    // ---- final BN + residual + factorized predictor ----
    score_kernel<<<score_grid, 256, 0, stream>>>(
        outbB, stats + 256, gamma + DD, beta + DD, x, Wc, s1, s2, invN, N);
    edge_pred_scalar<<<(Ep + 255) / 256, 256, 0, stream>>>(s1, s2, ei, bc, outp, Ep);
}

// Round 9
// 420.012 us; speedup vs baseline: 1.0146x; 1.0146x over previous
//
#include <hip/hip_runtime.h>
#include <hip/hip_bf16.h>
#include <hip/hip_fp16.h>

#define DD 128
#define BN_EPS 1e-5f

typedef __attribute__((ext_vector_type(8))) short bf16x8;
typedef __attribute__((ext_vector_type(4))) float f32x4;

static __device__ __forceinline__ unsigned short f2bf(float f) {
    __hip_bfloat16 h = __float2bfloat16(f);   // RNE
    return *reinterpret_cast<unsigned short*>(&h);
}
static __device__ __forceinline__ float bf2f(unsigned short u) {
    return __uint_as_float(((unsigned)u) << 16);
}
static __device__ __forceinline__ unsigned pack_rec(int col, float val) {
    __half h = __float2half(val);
    unsigned hb = *reinterpret_cast<unsigned short*>(&h);
    return (unsigned)col | (hb << 16);
}
static __device__ __forceinline__ float rec_val(unsigned rec) {
    unsigned short hb = (unsigned short)(rec >> 16);
    __half h = *reinterpret_cast<__half*>(&hb);
    return __half2float(h);
}

// ---------------------------------------------------------------- zero
__global__ __launch_bounds__(256) void zero_int_kernel(int* __restrict__ p, int n) {
    int i = blockIdx.x * 256 + threadIdx.x;
    if (i < n) p[i] = 0;
}

// ---------------------------------------------------------------- prep weights + histogram (fused)
__global__ __launch_bounds__(256) void prep_hist(
    const float* __restrict__ W, const float* __restrict__ Wself,
    unsigned short* __restrict__ Wt4,
    const int* __restrict__ arow, int* __restrict__ counts, int E)
{
    if (blockIdx.x < 4) {
        int mat = blockIdx.x;        // 0:L0 W, 1:L0 Wself, 2:L1 W, 3:L1 Wself
        int layer = mat >> 1;
        const float* src = (mat & 1) ? (Wself + layer * 16384) : (W + layer * 16384);
        unsigned short* dst = Wt4 + (size_t)mat * 16384;
        for (int i = threadIdx.x; i < 16384; i += 256) {
            int n = i >> 7, k = i & 127;
            dst[i] = f2bf(src[k * 128 + n]);
        }
    } else {
        int e = (blockIdx.x - 4) * 256 + threadIdx.x;
        if (e < E) atomicAdd(&counts[arow[e]], 1);
    }
}

// ---------------------------------------------------------------- scan (3 phases)
__global__ __launch_bounds__(256) void block_sums(
    const int* __restrict__ counts, int* __restrict__ bsums, int n)
{
    int base = blockIdx.x * 1024 + threadIdx.x * 4;
    int s = 0;
    #pragma unroll
    for (int j = 0; j < 4; j++) { int i = base + j; if (i < n) s += counts[i]; }
    #pragma unroll
    for (int off = 1; off < 64; off <<= 1) s += __shfl_xor(s, off);
    __shared__ int ws[4];
    int lane = threadIdx.x & 63, w = threadIdx.x >> 6;
    if (lane == 0) ws[w] = s;
    __syncthreads();
    if (threadIdx.x == 0) bsums[blockIdx.x] = ws[0] + ws[1] + ws[2] + ws[3];
}

__global__ __launch_bounds__(1024) void scan_bsums(
    int* __restrict__ bsums, int nb, int* __restrict__ offs, int n)
{
    __shared__ int sh[1024];
    int tid = threadIdx.x;
    int v = (tid < nb) ? bsums[tid] : 0;
    sh[tid] = v;
    __syncthreads();
    for (int off = 1; off < 1024; off <<= 1) {
        int t = (tid >= off) ? sh[tid - off] : 0;
        __syncthreads();
        sh[tid] += t;
        __syncthreads();
    }
    if (tid < nb) bsums[tid] = sh[tid] - v;   // exclusive
    if (tid == 0) offs[n] = sh[1023];         // grand total
}

__global__ __launch_bounds__(256) void scan_final(
    const int* __restrict__ counts, const int* __restrict__ bsums,
    int* __restrict__ offs, int* __restrict__ cursor, int n)
{
    int tid  = threadIdx.x;
    int base = blockIdx.x * 1024 + tid * 4;
    int c[4]; int s = 0;
    #pragma unroll
    for (int j = 0; j < 4; j++) { int i = base + j; c[j] = (i < n) ? counts[i] : 0; s += c[j]; }
    int lane = tid & 63, w = tid >> 6;
    int inc = s;
    #pragma unroll
    for (int off = 1; off < 64; off <<= 1) {
        int t = __shfl_up(inc, off);
        if (lane >= off) inc += t;
    }
    __shared__ int ws[4];
    if (lane == 63) ws[w] = inc;
    __syncthreads();
    int woff = 0;
    for (int k = 0; k < w; k++) woff += ws[k];
    int excl = bsums[blockIdx.x] + woff + inc - s;
    #pragma unroll
    for (int j = 0; j < 4; j++) {
        int i = base + j;
        if (i < n) { offs[i] = excl; cursor[i] = excl; }
        excl += c[j];
    }
}

// ---------------------------------------------------------------- XCD-partitioned scatter
__global__ __launch_bounds__(1024) void scatter_part(
    const int* __restrict__ arow, const int* __restrict__ acol,
    const float* __restrict__ aval, int* __restrict__ cursor,
    unsigned* __restrict__ packed, int E, int rpp)
{
    const int p     = blockIdx.x & 7;
    const int slice = blockIdx.x >> 3;
    const int nsl   = gridDim.x >> 3;
    const int e0    = (int)((long long)E * slice / nsl);
    const int e1    = (int)((long long)E * (slice + 1) / nsl);
    for (int e = e0 + threadIdx.x; e < e1; e += 1024) {
        int r = arow[e];
        if (r / rpp == p) {
            int pos = atomicAdd(&cursor[r], 1);
            packed[pos] = pack_rec(acol[e], aval[e]);
        }
    }
}

// ---------------------------------------------------------------- MFMA GEMM (+inline BN/ReLU on A)
__global__ __launch_bounds__(256) void gemm_mfma(
    const float* __restrict__ A,
    const unsigned short* __restrict__ Wt, const unsigned short* __restrict__ Wst,
    const float* __restrict__ bias,
    const float* __restrict__ stats, const float* __restrict__ gamma,
    const float* __restrict__ beta, float invN, int useBN,
    unsigned short* __restrict__ support, float* __restrict__ outb, int N)
{
    __shared__ float ssc[128], ssh[128];
    if (useBN) {
        if (threadIdx.x < 128) {
            int c = threadIdx.x;
            float mean = stats[c] * invN;
            float var  = stats[128 + c] * invN - mean * mean;
            float sc   = gamma[c] * rsqrtf(var + BN_EPS);
            ssc[c] = sc;
            ssh[c] = beta[c] - mean * sc;
        }
        __syncthreads();
    }

    const int wave = threadIdx.x >> 6;
    const int lane = threadIdx.x & 63;
    const int m    = lane & 15;
    const int quad = lane >> 4;
    const int row0 = blockIdx.x * 64 + wave * 16;

    int arow = row0 + m; if (arow > N - 1) arow = N - 1;
    const float* Ar = A + (size_t)arow * 128;
    bf16x8 af[4];
    #pragma unroll
    for (int ch = 0; ch < 4; ch++) {
        int k0 = ch * 32 + quad * 8;
        float4 u = *(const float4*)&Ar[k0];
        float4 v = *(const float4*)&Ar[k0 + 4];
        float vals[8] = {u.x, u.y, u.z, u.w, v.x, v.y, v.z, v.w};
        #pragma unroll
        for (int j = 0; j < 8; j++) {
            float val = vals[j];
            if (useBN) {
                val = val * ssc[k0 + j] + ssh[k0 + j];
                val = val > 0.f ? val : 0.f;
            }
            af[ch][j] = (short)f2bf(val);
        }
    }

    f32x4 acc1[8], acc2[8];
    #pragma unroll
    for (int nt = 0; nt < 8; nt++) {
        acc1[nt] = (f32x4)(0.f);
        acc2[nt] = (f32x4)(0.f);
    }

    #pragma unroll
    for (int nt = 0; nt < 8; nt++) {
        const bf16x8* B1 = (const bf16x8*)(Wt  + ((size_t)(nt * 16 + m)) * 128 + quad * 8);
        const bf16x8* B2 = (const bf16x8*)(Wst + ((size_t)(nt * 16 + m)) * 128 + quad * 8);
        acc1[nt] = __builtin_amdgcn_mfma_f32_16x16x32_bf16(af[0], B1[0],  acc1[nt], 0, 0, 0);
        acc2[nt] = __builtin_amdgcn_mfma_f32_16x16x32_bf16(af[0], B2[0],  acc2[nt], 0, 0, 0);
        acc1[nt] = __builtin_amdgcn_mfma_f32_16x16x32_bf16(af[1], B1[4],  acc1[nt], 0, 0, 0);
        acc2[nt] = __builtin_amdgcn_mfma_f32_16x16x32_bf16(af[1], B2[4],  acc2[nt], 0, 0, 0);
        acc1[nt] = __builtin_amdgcn_mfma_f32_16x16x32_bf16(af[2], B1[8],  acc1[nt], 0, 0, 0);
        acc2[nt] = __builtin_amdgcn_mfma_f32_16x16x32_bf16(af[2], B2[8],  acc2[nt], 0, 0, 0);
        acc1[nt] = __builtin_amdgcn_mfma_f32_16x16x32_bf16(af[3], B1[12], acc1[nt], 0, 0, 0);
        acc2[nt] = __builtin_amdgcn_mfma_f32_16x16x32_bf16(af[3], B2[12], acc2[nt], 0, 0, 0);
    }

    float bv[8];
    #pragma unroll
    for (int nt = 0; nt < 8; nt++) bv[nt] = bias[nt * 16 + m];

    // C/D layout: col = lane&15, row = quad*4 + reg
    #pragma unroll
    for (int r = 0; r < 4; r++) {
        int orow = row0 + quad * 4 + r;
        if (orow < N) {
            size_t base = (size_t)orow * 128 + m;
            #pragma unroll
            for (int nt = 0; nt < 8; nt++) {
                support[base + nt * 16] = f2bf(acc1[nt][r]);
                outb[base + nt * 16]    = acc2[nt][r] + bv[nt];
            }
        }
    }
}

// ---------------------------------------------------------------- SpMM + fused BN stats
// 32 lanes/row, 8 rows/block. ONE coalesced record load per 32 records + shfl
// broadcast; 4-deep gather unroll with two independent accumulator sets.
__global__ __launch_bounds__(256) void spmm_stats(
    const int* __restrict__ offs, const unsigned* __restrict__ packed,
    const unsigned short* __restrict__ sup, float* __restrict__ outb,
    float* __restrict__ stats, int ngroups, int N)
{
    const int r    = threadIdx.x & 31;   // column quad / record slot
    const int slot = threadIdx.x >> 5;   // row within group
    float s4[4] = {0.f, 0.f, 0.f, 0.f};
    float q4[4] = {0.f, 0.f, 0.f, 0.f};

    for (int g = blockIdx.x; g < ngroups; g += gridDim.x) {
        int row = g * 8 + slot;
        if (row >= N) continue;
        int beg = offs[row], end = offs[row + 1];

        float ax0 = 0.f, ay0 = 0.f, az0 = 0.f, aw0 = 0.f;
        float ax1 = 0.f, ay1 = 0.f, az1 = 0.f, aw1 = 0.f;

        for (int base = beg; base < end; base += 32) {
            int n = end - base; if (n > 32) n = 32;
            unsigned myrec = (r < n) ? packed[base + r] : 0u;
            int j = 0;
            for (; j + 4 <= n; j += 4) {
                unsigned p0 = __shfl((int)myrec, j + 0, 32);
                unsigned p1 = __shfl((int)myrec, j + 1, 32);
                unsigned p2 = __shfl((int)myrec, j + 2, 32);
                unsigned p3 = __shfl((int)myrec, j + 3, 32);
                ushort4 s0 = *(const ushort4*)&sup[((size_t)(p0 & 0xFFFFu) << 7) + r * 4];
                ushort4 s1 = *(const ushort4*)&sup[((size_t)(p1 & 0xFFFFu) << 7) + r * 4];
                ushort4 s2 = *(const ushort4*)&sup[((size_t)(p2 & 0xFFFFu) << 7) + r * 4];
                ushort4 s3 = *(const ushort4*)&sup[((size_t)(p3 & 0xFFFFu) << 7) + r * 4];
                float v0 = rec_val(p0), v1 = rec_val(p1);
                float v2 = rec_val(p2), v3 = rec_val(p3);
                ax0 += v0 * bf2f(s0.x); ay0 += v0 * bf2f(s0.y);
                az0 += v0 * bf2f(s0.z); aw0 += v0 * bf2f(s0.w);
                ax1 += v1 * bf2f(s1.x); ay1 += v1 * bf2f(s1.y);
                az1 += v1 * bf2f(s1.z); aw1 += v1 * bf2f(s1.w);
                ax0 += v2 * bf2f(s2.x); ay0 += v2 * bf2f(s2.y);
                az0 += v2 * bf2f(s2.z); aw0 += v2 * bf2f(s2.w);
                ax1 += v3 * bf2f(s3.x); ay1 += v3 * bf2f(s3.y);
                az1 += v3 * bf2f(s3.z); aw1 += v3 * bf2f(s3.w);
            }
            for (; j < n; j++) {
                unsigned pr = __shfl((int)myrec, j, 32);
                ushort4 sv = *(const ushort4*)&sup[((size_t)(pr & 0xFFFFu) << 7) + r * 4];
                float v = rec_val(pr);
                ax0 += v * bf2f(sv.x); ay0 += v * bf2f(sv.y);
                az0 += v * bf2f(sv.z); aw0 += v * bf2f(sv.w);
            }
        }

        float4* op = (float4*)&outb[((size_t)row << 7) + r * 4];
        float4 o = *op;
        o.x += ax0 + ax1; o.y += ay0 + ay1;
        o.z += az0 + az1; o.w += aw0 + aw1;
        *op = o;
        s4[0] += o.x; s4[1] += o.y; s4[2] += o.z; s4[3] += o.w;
        q4[0] += o.x * o.x; q4[1] += o.y * o.y; q4[2] += o.z * o.z; q4[3] += o.w * o.w;
    }

    __shared__ float red[8][128];
    #pragma unroll
    for (int j = 0; j < 4; j++) red[slot][r * 4 + j] = s4[j];
    __syncthreads();
    float ts = 0.f;
    if (threadIdx.x < 128) {
        #pragma unroll
        for (int j = 0; j < 8; j++) ts += red[j][threadIdx.x];
    }
    __syncthreads();
    #pragma unroll
    for (int j = 0; j < 4; j++) red[slot][r * 4 + j] = q4[j];
    __syncthreads();
    if (threadIdx.x < 128) {
        float tq = 0.f;
        #pragma unroll
        for (int j = 0; j < 8; j++) tq += red[j][threadIdx.x];
        atomicAdd(&stats[threadIdx.x], ts);
        atomicAdd(&stats[128 + threadIdx.x], tq);
    }
}

// ---------------------------------------------------------------- final BN + residual + score
__global__ __launch_bounds__(256) void score_kernel(
    const float* __restrict__ outb, const float* __restrict__ stats,
    const float* __restrict__ gamma, const float* __restrict__ beta,
    const float* __restrict__ x, const float* __restrict__ Wc,
    float* __restrict__ s1, float* __restrict__ s2, float invN, int N)
{
    int idx = blockIdx.x * 256 + threadIdx.x;
    if (idx >= N * 32) return;
    int c4 = (idx & 31) * 4;
    float4 o = *(const float4*)&outb[(size_t)idx * 4];
    float res[4];
    const float* op = &o.x;
    #pragma unroll
    for (int j = 0; j < 4; j++) {
        int c = c4 + j;
        float mean = stats[c] * invN;
        float var  = stats[128 + c] * invN - mean * mean;
        float sc   = gamma[c] * rsqrtf(var + BN_EPS);
        float sh   = beta[c] - mean * sc;
        float v    = op[j] * sc + sh;
        res[j] = v > 0.f ? v : 0.f;
    }
    float4 xv = *(const float4*)&x[(size_t)idx * 4];
    res[0] += xv.x; res[1] += xv.y; res[2] += xv.z; res[3] += xv.w;
    float4 w1 = *(const float4*)&Wc[c4];
    float4 w2 = *(const float4*)&Wc[128 + c4];
    float a1 = res[0] * w1.x + res[1] * w1.y + res[2] * w1.z + res[3] * w1.w;
    float a2 = res[0] * w2.x + res[1] * w2.y + res[2] * w2.z + res[3] * w2.w;
    #pragma unroll
    for (int off = 1; off < 32; off <<= 1) {
        a1 += __shfl_xor(a1, off);
        a2 += __shfl_xor(a2, off);
    }
    if ((idx & 31) == 0) {
        int row = idx >> 5;
        s1[row] = a1;
        s2[row] = a2;
    }
}

// ---------------------------------------------------------------- edge predictor (scalar)
__global__ __launch_bounds__(256) void edge_pred_scalar(
    const float* __restrict__ s1, const float* __restrict__ s2,
    const int* __restrict__ ei, const float* __restrict__ bc,
    float* __restrict__ outp, int Ep)
{
    int e = blockIdx.x * 256 + threadIdx.x;
    if (e >= Ep) return;
    float v = s1[ei[e]] + s2[ei[Ep + e]] + bc[0];
    outp[e] = 1.f / (1.f + expf(-v));
}

// ---------------------------------------------------------------- launch
extern "C" void kernel_launch(void* const* d_in, const int* in_sizes, int n_in,
                              void* d_out, int out_size, void* d_ws, size_t ws_size,
                              hipStream_t stream) {
    const float* x        = (const float*)d_in[0];
    const int*   adj_row  = (const int*)  d_in[1];
    const int*   adj_col  = (const int*)  d_in[2];
    const float* adj_val  = (const float*)d_in[3];
    const int*   ei       = (const int*)  d_in[4];
    const float* W        = (const float*)d_in[5];
    const float* W_self   = (const float*)d_in[6];
    const float* b        = (const float*)d_in[7];
    const float* gamma    = (const float*)d_in[8];
    const float* beta     = (const float*)d_in[9];
    const float* Wc       = (const float*)d_in[10];
    const float* bc       = (const float*)d_in[11];
    float* outp = (float*)d_out;

    const int N  = in_sizes[0] / DD;    // 50000
    const int E  = in_sizes[1];         // 800000
    const int Ep = in_sizes[4] / 2;     // 500000
    const float invN = 1.f / (float)N;

    size_t nd = (size_t)N * DD;
    char* p = (char*)d_ws;
    unsigned short* support16 = (unsigned short*)p; p += nd * 2;
    float*          outbA     = (float*)p;          p += nd * 4;
    float*          outbB     = (float*)p;          p += nd * 4;
    unsigned short* Wt4       = (unsigned short*)p; p += 4 * 16384 * 2;
    float*          stats     = (float*)p;          p += 512 * 4;   // contiguous with counts
    int*            counts    = (int*)p;            p += (size_t)N * 4;
    int*            offs      = (int*)p;            p += (size_t)(N + 2) * 4;
    int*            cursor    = (int*)p;            p += (size_t)N * 4;
    unsigned*       packed    = (unsigned*)p;       p += (size_t)E * 4;
    int*            bsums     = (int*)p;            p += 1024 * 4;
    float*          s1        = (float*)p;          p += (size_t)N * 4;
    float*          s2        = (float*)p;

    const int nb  = (N + 1023) / 1024;
    const int rpp = (N + 7) / 8;
    const int ngroups = (N + 7) / 8;

    zero_int_kernel<<<(512 + N + 255) / 256, 256, 0, stream>>>((int*)stats, 512 + N);
    prep_hist<<<4 + (E + 255) / 256, 256, 0, stream>>>(W, W_self, Wt4, adj_row, counts, E);
    block_sums<<<nb, 256, 0, stream>>>(counts, bsums, N);
    scan_bsums<<<1, 1024, 0, stream>>>(bsums, nb, offs, N);
    scan_final<<<nb, 256, 0, stream>>>(counts, bsums, offs, cursor, N);
    scatter_part<<<256, 1024, 0, stream>>>(adj_row, adj_col, adj_val, cursor, packed, E, rpp);

    const int gemm_grid  = (N + 63) / 64;
    const int score_grid = (N * 32 + 255) / 256;

    // ---- layer 0 ----
    gemm_mfma<<<gemm_grid, 256, 0, stream>>>(
        x, Wt4 + 0 * 16384, Wt4 + 1 * 16384, b,
        nullptr, nullptr, nullptr, invN, 0,
        support16, outbA, N);
    spmm_stats<<<2048, 256, 0, stream>>>(offs, packed, support16, outbA, stats, ngroups, N);

    // ---- layer 1 (BN of layer-0 fused into A staging) ----
    gemm_mfma<<<gemm_grid, 256, 0, stream>>>(
        outbA, Wt4 + 2 * 16384, Wt4 + 3 * 16384, b + DD,
        stats, gamma, beta, invN, 1,
        support16, outbB, N);
    spmm_stats<<<2048, 256, 0, stream>>>(offs, packed, support16, outbB, stats + 256, ngroups, N);

    // ---- final BN + residual + factorized predictor ----
    score_kernel<<<score_grid, 256, 0, stream>>>(
        outbB, stats + 256, gamma + DD, beta + DD, x, Wc, s1, s2, invN, N);
    edge_pred_scalar<<<(Ep + 255) / 256, 256, 0, stream>>>(s1, s2, ei, bc, outp, Ep);
}

// Round 10
// 376.794 us; speedup vs baseline: 1.1310x; 1.1147x over previous
//
#include <hip/hip_runtime.h>
#include <hip/hip_bf16.h>
#include <hip/hip_fp16.h>

#define DD 128
#define BN_EPS 1e-5f
#define SPMM_BLOCKS 2048

typedef __attribute__((ext_vector_type(8))) short bf16x8;
typedef __attribute__((ext_vector_type(4))) float f32x4;

static __device__ __forceinline__ unsigned short f2bf(float f) {
    __hip_bfloat16 h = __float2bfloat16(f);   // RNE
    return *reinterpret_cast<unsigned short*>(&h);
}
static __device__ __forceinline__ float bf2f(unsigned short u) {
    return __uint_as_float(((unsigned)u) << 16);
}
static __device__ __forceinline__ unsigned pack_rec(int col, float val) {
    __half h = __float2half(val);
    unsigned hb = *reinterpret_cast<unsigned short*>(&h);
    return (unsigned)col | (hb << 16);
}
static __device__ __forceinline__ float rec_val(unsigned rec) {
    unsigned short hb = (unsigned short)(rec >> 16);
    __half h = *reinterpret_cast<__half*>(&hb);
    return __half2float(h);
}

// ---------------------------------------------------------------- zero
__global__ __launch_bounds__(256) void zero_int_kernel(int* __restrict__ p, int n) {
    int i = blockIdx.x * 256 + threadIdx.x;
    if (i < n) p[i] = 0;
}

// ---------------------------------------------------------------- prep weights + histogram (fused)
__global__ __launch_bounds__(256) void prep_hist(
    const float* __restrict__ W, const float* __restrict__ Wself,
    unsigned short* __restrict__ Wt4,
    const int* __restrict__ arow, int* __restrict__ counts, int E)
{
    if (blockIdx.x < 4) {
        int mat = blockIdx.x;        // 0:L0 W, 1:L0 Wself, 2:L1 W, 3:L1 Wself
        int layer = mat >> 1;
        const float* src = (mat & 1) ? (Wself + layer * 16384) : (W + layer * 16384);
        unsigned short* dst = Wt4 + (size_t)mat * 16384;
        for (int i = threadIdx.x; i < 16384; i += 256) {
            int n = i >> 7, k = i & 127;
            dst[i] = f2bf(src[k * 128 + n]);
        }
    } else {
        int e = (blockIdx.x - 4) * 256 + threadIdx.x;
        if (e < E) atomicAdd(&counts[arow[e]], 1);
    }
}

// ---------------------------------------------------------------- scan (3 phases)
__global__ __launch_bounds__(256) void block_sums(
    const int* __restrict__ counts, int* __restrict__ bsums, int n)
{
    int base = blockIdx.x * 1024 + threadIdx.x * 4;
    int s = 0;
    #pragma unroll
    for (int j = 0; j < 4; j++) { int i = base + j; if (i < n) s += counts[i]; }
    #pragma unroll
    for (int off = 1; off < 64; off <<= 1) s += __shfl_xor(s, off);
    __shared__ int ws[4];
    int lane = threadIdx.x & 63, w = threadIdx.x >> 6;
    if (lane == 0) ws[w] = s;
    __syncthreads();
    if (threadIdx.x == 0) bsums[blockIdx.x] = ws[0] + ws[1] + ws[2] + ws[3];
}

__global__ __launch_bounds__(1024) void scan_bsums(
    int* __restrict__ bsums, int nb, int* __restrict__ offs, int n)
{
    __shared__ int sh[1024];
    int tid = threadIdx.x;
    int v = (tid < nb) ? bsums[tid] : 0;
    sh[tid] = v;
    __syncthreads();
    for (int off = 1; off < 1024; off <<= 1) {
        int t = (tid >= off) ? sh[tid - off] : 0;
        __syncthreads();
        sh[tid] += t;
        __syncthreads();
    }
    if (tid < nb) bsums[tid] = sh[tid] - v;   // exclusive
    if (tid == 0) offs[n] = sh[1023];         // grand total
}

__global__ __launch_bounds__(256) void scan_final(
    const int* __restrict__ counts, const int* __restrict__ bsums,
    int* __restrict__ offs, int* __restrict__ cursor, int n)
{
    int tid  = threadIdx.x;
    int base = blockIdx.x * 1024 + tid * 4;
    int c[4]; int s = 0;
    #pragma unroll
    for (int j = 0; j < 4; j++) { int i = base + j; c[j] = (i < n) ? counts[i] : 0; s += c[j]; }
    int lane = tid & 63, w = tid >> 6;
    int inc = s;
    #pragma unroll
    for (int off = 1; off < 64; off <<= 1) {
        int t = __shfl_up(inc, off);
        if (lane >= off) inc += t;
    }
    __shared__ int ws[4];
    if (lane == 63) ws[w] = inc;
    __syncthreads();
    int woff = 0;
    for (int k = 0; k < w; k++) woff += ws[k];
    int excl = bsums[blockIdx.x] + woff + inc - s;
    #pragma unroll
    for (int j = 0; j < 4; j++) {
        int i = base + j;
        if (i < n) { offs[i] = excl; cursor[i] = excl; }
        excl += c[j];
    }
}

// ---------------------------------------------------------------- XCD-partitioned scatter
__global__ __launch_bounds__(1024) void scatter_part(
    const int* __restrict__ arow, const int* __restrict__ acol,
    const float* __restrict__ aval, int* __restrict__ cursor,
    unsigned* __restrict__ packed, int E, int rpp)
{
    const int p     = blockIdx.x & 7;
    const int slice = blockIdx.x >> 3;
    const int nsl   = gridDim.x >> 3;
    const int e0    = (int)((long long)E * slice / nsl);
    const int e1    = (int)((long long)E * (slice + 1) / nsl);
    for (int e = e0 + threadIdx.x; e < e1; e += 1024) {
        int r = arow[e];
        if (r / rpp == p) {
            int pos = atomicAdd(&cursor[r], 1);
            packed[pos] = pack_rec(acol[e], aval[e]);
        }
    }
}

// ---------------------------------------------------------------- MFMA GEMM (+inline BN/ReLU on A)
__global__ __launch_bounds__(256) void gemm_mfma(
    const float* __restrict__ A,
    const unsigned short* __restrict__ Wt, const unsigned short* __restrict__ Wst,
    const float* __restrict__ bias,
    const float* __restrict__ stats, const float* __restrict__ gamma,
    const float* __restrict__ beta, float invN, int useBN,
    unsigned short* __restrict__ support, float* __restrict__ outb, int N)
{
    __shared__ float ssc[128], ssh[128];
    if (useBN) {
        if (threadIdx.x < 128) {
            int c = threadIdx.x;
            float mean = stats[c] * invN;
            float var  = stats[128 + c] * invN - mean * mean;
            float sc   = gamma[c] * rsqrtf(var + BN_EPS);
            ssc[c] = sc;
            ssh[c] = beta[c] - mean * sc;
        }
        __syncthreads();
    }

    const int wave = threadIdx.x >> 6;
    const int lane = threadIdx.x & 63;
    const int m    = lane & 15;
    const int quad = lane >> 4;
    const int row0 = blockIdx.x * 64 + wave * 16;

    int arow = row0 + m; if (arow > N - 1) arow = N - 1;
    const float* Ar = A + (size_t)arow * 128;
    bf16x8 af[4];
    #pragma unroll
    for (int ch = 0; ch < 4; ch++) {
        int k0 = ch * 32 + quad * 8;
        float4 u = *(const float4*)&Ar[k0];
        float4 v = *(const float4*)&Ar[k0 + 4];
        float vals[8] = {u.x, u.y, u.z, u.w, v.x, v.y, v.z, v.w};
        #pragma unroll
        for (int j = 0; j < 8; j++) {
            float val = vals[j];
            if (useBN) {
                val = val * ssc[k0 + j] + ssh[k0 + j];
                val = val > 0.f ? val : 0.f;
            }
            af[ch][j] = (short)f2bf(val);
        }
    }

    f32x4 acc1[8], acc2[8];
    #pragma unroll
    for (int nt = 0; nt < 8; nt++) {
        acc1[nt] = (f32x4)(0.f);
        acc2[nt] = (f32x4)(0.f);
    }

    #pragma unroll
    for (int nt = 0; nt < 8; nt++) {
        const bf16x8* B1 = (const bf16x8*)(Wt  + ((size_t)(nt * 16 + m)) * 128 + quad * 8);
        const bf16x8* B2 = (const bf16x8*)(Wst + ((size_t)(nt * 16 + m)) * 128 + quad * 8);
        acc1[nt] = __builtin_amdgcn_mfma_f32_16x16x32_bf16(af[0], B1[0],  acc1[nt], 0, 0, 0);
        acc2[nt] = __builtin_amdgcn_mfma_f32_16x16x32_bf16(af[0], B2[0],  acc2[nt], 0, 0, 0);
        acc1[nt] = __builtin_amdgcn_mfma_f32_16x16x32_bf16(af[1], B1[4],  acc1[nt], 0, 0, 0);
        acc2[nt] = __builtin_amdgcn_mfma_f32_16x16x32_bf16(af[1], B2[4],  acc2[nt], 0, 0, 0);
        acc1[nt] = __builtin_amdgcn_mfma_f32_16x16x32_bf16(af[2], B1[8],  acc1[nt], 0, 0, 0);
        acc2[nt] = __builtin_amdgcn_mfma_f32_16x16x32_bf16(af[2], B2[8],  acc2[nt], 0, 0, 0);
        acc1[nt] = __builtin_amdgcn_mfma_f32_16x16x32_bf16(af[3], B1[12], acc1[nt], 0, 0, 0);
        acc2[nt] = __builtin_amdgcn_mfma_f32_16x16x32_bf16(af[3], B2[12], acc2[nt], 0, 0, 0);
    }

    float bv[8];
    #pragma unroll
    for (int nt = 0; nt < 8; nt++) bv[nt] = bias[nt * 16 + m];

    // C/D layout: col = lane&15, row = quad*4 + reg
    #pragma unroll
    for (int r = 0; r < 4; r++) {
        int orow = row0 + quad * 4 + r;
        if (orow < N) {
            size_t base = (size_t)orow * 128 + m;
            #pragma unroll
            for (int nt = 0; nt < 8; nt++) {
                support[base + nt * 16] = f2bf(acc1[nt][r]);
                outb[base + nt * 16]    = acc2[nt][r] + bv[nt];
            }
        }
    }
}

// ---------------------------------------------------------------- SpMM + fused BN stats
// 32 lanes/row, 8 rows/block, grid-stride. R7-style broadcast record loads,
// 4-deep gather unroll. Stats: per-block NON-ATOMIC partials (atomic storm
// removed — that was the R8/R9 regression).
__global__ __launch_bounds__(256) void spmm_stats(
    const int* __restrict__ offs, const unsigned* __restrict__ packed,
    const unsigned short* __restrict__ sup, float* __restrict__ outb,
    float* __restrict__ partials, int ngroups, int N)
{
    const int r    = threadIdx.x & 31;   // column quad
    const int slot = threadIdx.x >> 5;   // row within group
    float s4[4] = {0.f, 0.f, 0.f, 0.f};
    float q4[4] = {0.f, 0.f, 0.f, 0.f};

    for (int g = blockIdx.x; g < ngroups; g += gridDim.x) {
        int row = g * 8 + slot;
        if (row >= N) continue;
        int beg = offs[row], end = offs[row + 1];

        float4 acc = make_float4(0.f, 0.f, 0.f, 0.f);
        int e = beg;
        for (; e + 4 <= end; e += 4) {
            unsigned p0 = packed[e + 0];
            unsigned p1 = packed[e + 1];
            unsigned p2 = packed[e + 2];
            unsigned p3 = packed[e + 3];
            ushort4 s0 = *(const ushort4*)&sup[((size_t)(p0 & 0xFFFFu) << 7) + r * 4];
            ushort4 s1 = *(const ushort4*)&sup[((size_t)(p1 & 0xFFFFu) << 7) + r * 4];
            ushort4 s2 = *(const ushort4*)&sup[((size_t)(p2 & 0xFFFFu) << 7) + r * 4];
            ushort4 s3 = *(const ushort4*)&sup[((size_t)(p3 & 0xFFFFu) << 7) + r * 4];
            float v0 = rec_val(p0), v1 = rec_val(p1);
            float v2 = rec_val(p2), v3 = rec_val(p3);
            acc.x += v0 * bf2f(s0.x); acc.y += v0 * bf2f(s0.y);
            acc.z += v0 * bf2f(s0.z); acc.w += v0 * bf2f(s0.w);
            acc.x += v1 * bf2f(s1.x); acc.y += v1 * bf2f(s1.y);
            acc.z += v1 * bf2f(s1.z); acc.w += v1 * bf2f(s1.w);
            acc.x += v2 * bf2f(s2.x); acc.y += v2 * bf2f(s2.y);
            acc.z += v2 * bf2f(s2.z); acc.w += v2 * bf2f(s2.w);
            acc.x += v3 * bf2f(s3.x); acc.y += v3 * bf2f(s3.y);
            acc.z += v3 * bf2f(s3.z); acc.w += v3 * bf2f(s3.w);
        }
        for (; e < end; e++) {
            unsigned pr = packed[e];
            ushort4 sv = *(const ushort4*)&sup[((size_t)(pr & 0xFFFFu) << 7) + r * 4];
            float v = rec_val(pr);
            acc.x += v * bf2f(sv.x); acc.y += v * bf2f(sv.y);
            acc.z += v * bf2f(sv.z); acc.w += v * bf2f(sv.w);
        }

        float4* op = (float4*)&outb[((size_t)row << 7) + r * 4];
        float4 o = *op;
        o.x += acc.x; o.y += acc.y; o.z += acc.z; o.w += acc.w;
        *op = o;
        s4[0] += o.x; s4[1] += o.y; s4[2] += o.z; s4[3] += o.w;
        q4[0] += o.x * o.x; q4[1] += o.y * o.y; q4[2] += o.z * o.z; q4[3] += o.w * o.w;
    }

    __shared__ float red[8][128];
    #pragma unroll
    for (int j = 0; j < 4; j++) red[slot][r * 4 + j] = s4[j];
    __syncthreads();
    float ts = 0.f;
    if (threadIdx.x < 128) {
        #pragma unroll
        for (int j = 0; j < 8; j++) ts += red[j][threadIdx.x];
        partials[(size_t)blockIdx.x * 256 + threadIdx.x] = ts;   // non-atomic
    }
    __syncthreads();
    #pragma unroll
    for (int j = 0; j < 4; j++) red[slot][r * 4 + j] = q4[j];
    __syncthreads();
    if (threadIdx.x < 128) {
        float tq = 0.f;
        #pragma unroll
        for (int j = 0; j < 8; j++) tq += red[j][threadIdx.x];
        partials[(size_t)blockIdx.x * 256 + 128 + threadIdx.x] = tq;
    }
}

// ---------------------------------------------------------------- partials -> stats
// 32 blocks; block g folds partial rows [g*64, g*64+64). Coalesced reads,
// 512 atomics/block spread over 256 addresses (16k total — negligible).
__global__ __launch_bounds__(256) void reduce_stats(
    const float* __restrict__ partials, float* __restrict__ stats, int nblk)
{
    int g = blockIdx.x;
    int per = (nblk + gridDim.x - 1) / gridDim.x;
    int b0 = g * per, b1 = min(b0 + per, nblk);
    float a0 = 0.f, a1 = 0.f;
    for (int b = b0; b < b1; b++) {
        a0 += partials[(size_t)b * 256 + threadIdx.x];
    }
    atomicAdd(&stats[threadIdx.x], a0);
    (void)a1;
}

// ---------------------------------------------------------------- final BN + residual + score
__global__ __launch_bounds__(256) void score_kernel(
    const float* __restrict__ outb, const float* __restrict__ stats,
    const float* __restrict__ gamma, const float* __restrict__ beta,
    const float* __restrict__ x, const float* __restrict__ Wc,
    float* __restrict__ s1, float* __restrict__ s2, float invN, int N)
{
    int idx = blockIdx.x * 256 + threadIdx.x;
    if (idx >= N * 32) return;
    int c4 = (idx & 31) * 4;
    float4 o = *(const float4*)&outb[(size_t)idx * 4];
    float res[4];
    const float* op = &o.x;
    #pragma unroll
    for (int j = 0; j < 4; j++) {
        int c = c4 + j;
        float mean = stats[c] * invN;
        float var  = stats[128 + c] * invN - mean * mean;
        float sc   = gamma[c] * rsqrtf(var + BN_EPS);
        float sh   = beta[c] - mean * sc;
        float v    = op[j] * sc + sh;
        res[j] = v > 0.f ? v : 0.f;
    }
    float4 xv = *(const float4*)&x[(size_t)idx * 4];
    res[0] += xv.x; res[1] += xv.y; res[2] += xv.z; res[3] += xv.w;
    float4 w1 = *(const float4*)&Wc[c4];
    float4 w2 = *(const float4*)&Wc[128 + c4];
    float a1 = res[0] * w1.x + res[1] * w1.y + res[2] * w1.z + res[3] * w1.w;
    float a2 = res[0] * w2.x + res[1] * w2.y + res[2] * w2.z + res[3] * w2.w;
    #pragma unroll
    for (int off = 1; off < 32; off <<= 1) {
        a1 += __shfl_xor(a1, off);
        a2 += __shfl_xor(a2, off);
    }
    if ((idx & 31) == 0) {
        int row = idx >> 5;
        s1[row] = a1;
        s2[row] = a2;
    }
}

// ---------------------------------------------------------------- edge predictor (scalar)
__global__ __launch_bounds__(256) void edge_pred_scalar(
    const float* __restrict__ s1, const float* __restrict__ s2,
    const int* __restrict__ ei, const float* __restrict__ bc,
    float* __restrict__ outp, int Ep)
{
    int e = blockIdx.x * 256 + threadIdx.x;
    if (e >= Ep) return;
    float v = s1[ei[e]] + s2[ei[Ep + e]] + bc[0];
    outp[e] = 1.f / (1.f + expf(-v));
}

// ---------------------------------------------------------------- launch
extern "C" void kernel_launch(void* const* d_in, const int* in_sizes, int n_in,
                              void* d_out, int out_size, void* d_ws, size_t ws_size,
                              hipStream_t stream) {
    const float* x        = (const float*)d_in[0];
    const int*   adj_row  = (const int*)  d_in[1];
    const int*   adj_col  = (const int*)  d_in[2];
    const float* adj_val  = (const float*)d_in[3];
    const int*   ei       = (const int*)  d_in[4];
    const float* W        = (const float*)d_in[5];
    const float* W_self   = (const float*)d_in[6];
    const float* b        = (const float*)d_in[7];
    const float* gamma    = (const float*)d_in[8];
    const float* beta     = (const float*)d_in[9];
    const float* Wc       = (const float*)d_in[10];
    const float* bc       = (const float*)d_in[11];
    float* outp = (float*)d_out;

    const int N  = in_sizes[0] / DD;    // 50000
    const int E  = in_sizes[1];         // 800000
    const int Ep = in_sizes[4] / 2;     // 500000
    const float invN = 1.f / (float)N;

    size_t nd = (size_t)N * DD;
    char* p = (char*)d_ws;
    unsigned short* support16 = (unsigned short*)p; p += nd * 2;
    float*          outbA     = (float*)p;          p += nd * 4;
    float*          outbB     = (float*)p;          p += nd * 4;
    unsigned short* Wt4       = (unsigned short*)p; p += 4 * 16384 * 2;
    float*          stats     = (float*)p;          p += 512 * 4;   // contiguous with counts
    int*            counts    = (int*)p;            p += (size_t)N * 4;
    int*            offs      = (int*)p;            p += (size_t)(N + 2) * 4;
    int*            cursor    = (int*)p;            p += (size_t)N * 4;
    unsigned*       packed    = (unsigned*)p;       p += (size_t)E * 4;
    int*            bsums     = (int*)p;            p += 1024 * 4;
    float*          s1        = (float*)p;          p += (size_t)N * 4;
    float*          s2        = (float*)p;          p += (size_t)N * 4;
    float*          partials  = (float*)p;          p += (size_t)SPMM_BLOCKS * 256 * 4;

    const int nb  = (N + 1023) / 1024;
    const int rpp = (N + 7) / 8;
    const int ngroups = (N + 7) / 8;

    zero_int_kernel<<<(512 + N + 255) / 256, 256, 0, stream>>>((int*)stats, 512 + N);
    prep_hist<<<4 + (E + 255) / 256, 256, 0, stream>>>(W, W_self, Wt4, adj_row, counts, E);
    block_sums<<<nb, 256, 0, stream>>>(counts, bsums, N);
    scan_bsums<<<1, 1024, 0, stream>>>(bsums, nb, offs, N);
    scan_final<<<nb, 256, 0, stream>>>(counts, bsums, offs, cursor, N);
    scatter_part<<<256, 1024, 0, stream>>>(adj_row, adj_col, adj_val, cursor, packed, E, rpp);

    const int gemm_grid  = (N + 63) / 64;
    const int score_grid = (N * 32 + 255) / 256;

    // ---- layer 0 ----
    gemm_mfma<<<gemm_grid, 256, 0, stream>>>(
        x, Wt4 + 0 * 16384, Wt4 + 1 * 16384, b,
        nullptr, nullptr, nullptr, invN, 0,
        support16, outbA, N);
    spmm_stats<<<SPMM_BLOCKS, 256, 0, stream>>>(offs, packed, support16, outbA, partials, ngroups, N);
    reduce_stats<<<32, 256, 0, stream>>>(partials, stats, SPMM_BLOCKS);

    // ---- layer 1 (BN of layer-0 fused into A staging) ----
    gemm_mfma<<<gemm_grid, 256, 0, stream>>>(
        outbA, Wt4 + 2 * 16384, Wt4 + 3 * 16384, b + DD,
        stats, gamma, beta, invN, 1,
        support16, outbB, N);
    spmm_stats<<<SPMM_BLOCKS, 256, 0, stream>>>(offs, packed, support16, outbB, partials, ngroups, N);
    reduce_stats<<<32, 256, 0, stream>>>(partials, stats + 256, SPMM_BLOCKS);

    // ---- final BN + residual + factorized predictor ----
    score_kernel<<<score_grid, 256, 0, stream>>>(
        outbB, stats + 256, gamma + DD, beta + DD, x, Wc, s1, s2, invN, N);
    edge_pred_scalar<<<(Ep + 255) / 256, 256, 0, stream>>>(s1, s2, ei, bc, outp, Ep);
}

// Round 11
// 332.835 us; speedup vs baseline: 1.2803x; 1.1321x over previous
//
#include <hip/hip_runtime.h>
#include <hip/hip_bf16.h>
#include <hip/hip_fp16.h>

#define DD 128
#define BN_EPS 1e-5f
#define SPMM_BLOCKS 2048
#define CAP 64           // bucket capacity per row (Poisson(16) -> overflow ~1e-15)
#define OVF_MAX 4096

typedef __attribute__((ext_vector_type(8))) short bf16x8;
typedef __attribute__((ext_vector_type(4))) float f32x4;

static __device__ __forceinline__ unsigned short f2bf(float f) {
    __hip_bfloat16 h = __float2bfloat16(f);   // RNE
    return *reinterpret_cast<unsigned short*>(&h);
}
static __device__ __forceinline__ float bf2f(unsigned short u) {
    return __uint_as_float(((unsigned)u) << 16);
}
static __device__ __forceinline__ unsigned pack_rec(int col, float val) {
    __half h = __float2half(val);
    unsigned hb = *reinterpret_cast<unsigned short*>(&h);
    return (unsigned)col | (hb << 16);
}
static __device__ __forceinline__ float rec_val(unsigned rec) {
    unsigned short hb = (unsigned short)(rec >> 16);
    __half h = *reinterpret_cast<__half*>(&hb);
    return __half2float(h);
}

// ---------------------------------------------------------------- prep + zero (fused)
// blocks 0..31: weight transpose/convert (coalesced reads, strided writes)
// blocks 32.. : zero ints (stats + cnt + ovfc)
__global__ __launch_bounds__(256) void prep_zero(
    const float* __restrict__ W, const float* __restrict__ Wself,
    unsigned short* __restrict__ Wt4, int* __restrict__ zp, int nz)
{
    if (blockIdx.x < 32) {
        int mat   = blockIdx.x >> 3;       // 0:L0 W, 1:L0 Wself, 2:L1 W, 3:L1 Wself
        int chunk = blockIdx.x & 7;
        int layer = mat >> 1;
        const float* src = (mat & 1) ? (Wself + layer * 16384) : (W + layer * 16384);
        unsigned short* dst = Wt4 + (size_t)mat * 16384;
        // linear read (coalesced), transposed write (strided, buffered)
        int base = chunk * 2048 + threadIdx.x * 4;
        #pragma unroll
        for (int rep = 0; rep < 2; rep++) {
            int i = base + rep * 1024;          // i = k*128 + n
            float4 v = *(const float4*)&src[i];
            int k = i >> 7, n = i & 127;
            dst[(n + 0) * 128 + k] = f2bf(v.x);
            dst[(n + 1) * 128 + k] = f2bf(v.y);
            dst[(n + 2) * 128 + k] = f2bf(v.z);
            dst[(n + 3) * 128 + k] = f2bf(v.w);
        }
    } else {
        int i = (blockIdx.x - 32) * 256 + threadIdx.x;
        if (i < nz) zp[i] = 0;
    }
}

// ---------------------------------------------------------------- single-pass bucket scatter
// XCD-partitioned: partition p = blockIdx&7 handles rows [p*rpp, (p+1)*rpp)
__global__ __launch_bounds__(1024) void scatter_bucket(
    const int* __restrict__ arow, const int* __restrict__ acol,
    const float* __restrict__ aval, int* __restrict__ cnt,
    unsigned* __restrict__ bucket, int* __restrict__ ovfc,
    int2* __restrict__ ovf, int E, int rpp)
{
    const int p     = blockIdx.x & 7;
    const int slice = blockIdx.x >> 3;
    const int nsl   = gridDim.x >> 3;
    const int e0    = (int)((long long)E * slice / nsl);
    const int e1    = (int)((long long)E * (slice + 1) / nsl);
    for (int e = e0 + threadIdx.x; e < e1; e += 1024) {
        int r = arow[e];
        if (r / rpp == p) {
            int pos = atomicAdd(&cnt[r], 1);
            unsigned rec = pack_rec(acol[e], aval[e]);
            if (pos < CAP) {
                __builtin_nontemporal_store(rec, &bucket[(size_t)r * CAP + pos]);
            } else {
                int oi = atomicAdd(ovfc, 1);
                if (oi < OVF_MAX) ovf[oi] = make_int2(r, (int)rec);
            }
        }
    }
}

// ---------------------------------------------------------------- MFMA GEMM (+inline BN/ReLU on A)
__global__ __launch_bounds__(256) void gemm_mfma(
    const float* __restrict__ A,
    const unsigned short* __restrict__ Wt, const unsigned short* __restrict__ Wst,
    const float* __restrict__ bias,
    const float* __restrict__ stats, const float* __restrict__ gamma,
    const float* __restrict__ beta, float invN, int useBN,
    unsigned short* __restrict__ support, float* __restrict__ outb, int N)
{
    __shared__ float ssc[128], ssh[128];
    if (useBN) {
        if (threadIdx.x < 128) {
            int c = threadIdx.x;
            float mean = stats[c] * invN;
            float var  = stats[128 + c] * invN - mean * mean;
            float sc   = gamma[c] * rsqrtf(var + BN_EPS);
            ssc[c] = sc;
            ssh[c] = beta[c] - mean * sc;
        }
        __syncthreads();
    }

    const int wave = threadIdx.x >> 6;
    const int lane = threadIdx.x & 63;
    const int m    = lane & 15;
    const int quad = lane >> 4;
    const int row0 = blockIdx.x * 64 + wave * 16;

    int arow = row0 + m; if (arow > N - 1) arow = N - 1;
    const float* Ar = A + (size_t)arow * 128;
    bf16x8 af[4];
    #pragma unroll
    for (int ch = 0; ch < 4; ch++) {
        int k0 = ch * 32 + quad * 8;
        float4 u = *(const float4*)&Ar[k0];
        float4 v = *(const float4*)&Ar[k0 + 4];
        float vals[8] = {u.x, u.y, u.z, u.w, v.x, v.y, v.z, v.w};
        #pragma unroll
        for (int j = 0; j < 8; j++) {
            float val = vals[j];
            if (useBN) {
                val = val * ssc[k0 + j] + ssh[k0 + j];
                val = val > 0.f ? val : 0.f;
            }
            af[ch][j] = (short)f2bf(val);
        }
    }

    f32x4 acc1[8], acc2[8];
    #pragma unroll
    for (int nt = 0; nt < 8; nt++) {
        acc1[nt] = (f32x4)(0.f);
        acc2[nt] = (f32x4)(0.f);
    }

    #pragma unroll
    for (int nt = 0; nt < 8; nt++) {
        const bf16x8* B1 = (const bf16x8*)(Wt  + ((size_t)(nt * 16 + m)) * 128 + quad * 8);
        const bf16x8* B2 = (const bf16x8*)(Wst + ((size_t)(nt * 16 + m)) * 128 + quad * 8);
        acc1[nt] = __builtin_amdgcn_mfma_f32_16x16x32_bf16(af[0], B1[0],  acc1[nt], 0, 0, 0);
        acc2[nt] = __builtin_amdgcn_mfma_f32_16x16x32_bf16(af[0], B2[0],  acc2[nt], 0, 0, 0);
        acc1[nt] = __builtin_amdgcn_mfma_f32_16x16x32_bf16(af[1], B1[4],  acc1[nt], 0, 0, 0);
        acc2[nt] = __builtin_amdgcn_mfma_f32_16x16x32_bf16(af[1], B2[4],  acc2[nt], 0, 0, 0);
        acc1[nt] = __builtin_amdgcn_mfma_f32_16x16x32_bf16(af[2], B1[8],  acc1[nt], 0, 0, 0);
        acc2[nt] = __builtin_amdgcn_mfma_f32_16x16x32_bf16(af[2], B2[8],  acc2[nt], 0, 0, 0);
        acc1[nt] = __builtin_amdgcn_mfma_f32_16x16x32_bf16(af[3], B1[12], acc1[nt], 0, 0, 0);
        acc2[nt] = __builtin_amdgcn_mfma_f32_16x16x32_bf16(af[3], B2[12], acc2[nt], 0, 0, 0);
    }

    float bv[8];
    #pragma unroll
    for (int nt = 0; nt < 8; nt++) bv[nt] = bias[nt * 16 + m];

    // C/D layout: col = lane&15, row = quad*4 + reg
    #pragma unroll
    for (int r = 0; r < 4; r++) {
        int orow = row0 + quad * 4 + r;
        if (orow < N) {
            size_t base = (size_t)orow * 128 + m;
            #pragma unroll
            for (int nt = 0; nt < 8; nt++) {
                support[base + nt * 16] = f2bf(acc1[nt][r]);
                outb[base + nt * 16]    = acc2[nt][r] + bv[nt];
            }
        }
    }
}

// ---------------------------------------------------------------- SpMM (bucket) + fused BN stats
__global__ __launch_bounds__(256) void spmm_stats(
    const int* __restrict__ cnt, const unsigned* __restrict__ bucket,
    const int* __restrict__ ovfc, const int2* __restrict__ ovf,
    const unsigned short* __restrict__ sup, float* __restrict__ outb,
    float* __restrict__ partials, int ngroups, int N)
{
    const int r    = threadIdx.x & 31;   // column quad
    const int slot = threadIdx.x >> 5;   // row within group
    float s4[4] = {0.f, 0.f, 0.f, 0.f};
    float q4[4] = {0.f, 0.f, 0.f, 0.f};

    for (int g = blockIdx.x; g < ngroups; g += gridDim.x) {
        int row = g * 8 + slot;
        if (row >= N) continue;
        int nrec = cnt[row]; if (nrec > CAP) nrec = CAP;
        const unsigned* packed = bucket + (size_t)row * CAP;

        float4 acc = make_float4(0.f, 0.f, 0.f, 0.f);
        int e = 0;
        for (; e + 4 <= nrec; e += 4) {
            unsigned p0 = packed[e + 0];
            unsigned p1 = packed[e + 1];
            unsigned p2 = packed[e + 2];
            unsigned p3 = packed[e + 3];
            ushort4 s0 = *(const ushort4*)&sup[((size_t)(p0 & 0xFFFFu) << 7) + r * 4];
            ushort4 s1 = *(const ushort4*)&sup[((size_t)(p1 & 0xFFFFu) << 7) + r * 4];
            ushort4 s2 = *(const ushort4*)&sup[((size_t)(p2 & 0xFFFFu) << 7) + r * 4];
            ushort4 s3 = *(const ushort4*)&sup[((size_t)(p3 & 0xFFFFu) << 7) + r * 4];
            float v0 = rec_val(p0), v1 = rec_val(p1);
            float v2 = rec_val(p2), v3 = rec_val(p3);
            acc.x += v0 * bf2f(s0.x); acc.y += v0 * bf2f(s0.y);
            acc.z += v0 * bf2f(s0.z); acc.w += v0 * bf2f(s0.w);
            acc.x += v1 * bf2f(s1.x); acc.y += v1 * bf2f(s1.y);
            acc.z += v1 * bf2f(s1.z); acc.w += v1 * bf2f(s1.w);
            acc.x += v2 * bf2f(s2.x); acc.y += v2 * bf2f(s2.y);
            acc.z += v2 * bf2f(s2.z); acc.w += v2 * bf2f(s2.w);
            acc.x += v3 * bf2f(s3.x); acc.y += v3 * bf2f(s3.y);
            acc.z += v3 * bf2f(s3.z); acc.w += v3 * bf2f(s3.w);
        }
        for (; e < nrec; e++) {
            unsigned pr = packed[e];
            ushort4 sv = *(const ushort4*)&sup[((size_t)(pr & 0xFFFFu) << 7) + r * 4];
            float v = rec_val(pr);
            acc.x += v * bf2f(sv.x); acc.y += v * bf2f(sv.y);
            acc.z += v * bf2f(sv.z); acc.w += v * bf2f(sv.w);
        }

        // overflow records (expected 0; exactness safety net)
        int oc = *ovfc;
        if (oc > 0) {
            if (oc > OVF_MAX) oc = OVF_MAX;
            for (int i = 0; i < oc; i++) {
                int2 orec = ovf[i];
                if (orec.x == row) {
                    unsigned pr = (unsigned)orec.y;
                    ushort4 sv = *(const ushort4*)&sup[((size_t)(pr & 0xFFFFu) << 7) + r * 4];
                    float v = rec_val(pr);
                    acc.x += v * bf2f(sv.x); acc.y += v * bf2f(sv.y);
                    acc.z += v * bf2f(sv.z); acc.w += v * bf2f(sv.w);
                }
            }
        }

        float4* op = (float4*)&outb[((size_t)row << 7) + r * 4];
        float4 o = *op;
        o.x += acc.x; o.y += acc.y; o.z += acc.z; o.w += acc.w;
        *op = o;
        s4[0] += o.x; s4[1] += o.y; s4[2] += o.z; s4[3] += o.w;
        q4[0] += o.x * o.x; q4[1] += o.y * o.y; q4[2] += o.z * o.z; q4[3] += o.w * o.w;
    }

    __shared__ float red[8][128];
    #pragma unroll
    for (int j = 0; j < 4; j++) red[slot][r * 4 + j] = s4[j];
    __syncthreads();
    float ts = 0.f;
    if (threadIdx.x < 128) {
        #pragma unroll
        for (int j = 0; j < 8; j++) ts += red[j][threadIdx.x];
        partials[(size_t)blockIdx.x * 256 + threadIdx.x] = ts;   // non-atomic
    }
    __syncthreads();
    #pragma unroll
    for (int j = 0; j < 4; j++) red[slot][r * 4 + j] = q4[j];
    __syncthreads();
    if (threadIdx.x < 128) {
        float tq = 0.f;
        #pragma unroll
        for (int j = 0; j < 8; j++) tq += red[j][threadIdx.x];
        partials[(size_t)blockIdx.x * 256 + 128 + threadIdx.x] = tq;
    }
}

// ---------------------------------------------------------------- partials -> stats
__global__ __launch_bounds__(256) void reduce_stats(
    const float* __restrict__ partials, float* __restrict__ stats, int nblk)
{
    int g = blockIdx.x;
    int per = (nblk + gridDim.x - 1) / gridDim.x;
    int b0 = g * per, b1 = min(b0 + per, nblk);
    float a0 = 0.f;
    for (int b = b0; b < b1; b++) {
        a0 += partials[(size_t)b * 256 + threadIdx.x];
    }
    atomicAdd(&stats[threadIdx.x], a0);
}

// ---------------------------------------------------------------- final BN + residual + score
__global__ __launch_bounds__(256) void score_kernel(
    const float* __restrict__ outb, const float* __restrict__ stats,
    const float* __restrict__ gamma, const float* __restrict__ beta,
    const float* __restrict__ x, const float* __restrict__ Wc,
    float* __restrict__ s1, float* __restrict__ s2, float invN, int N)
{
    int idx = blockIdx.x * 256 + threadIdx.x;
    if (idx >= N * 32) return;
    int c4 = (idx & 31) * 4;
    float4 o = *(const float4*)&outb[(size_t)idx * 4];
    float res[4];
    const float* op = &o.x;
    #pragma unroll
    for (int j = 0; j < 4; j++) {
        int c = c4 + j;
        float mean = stats[c] * invN;
        float var  = stats[128 + c] * invN - mean * mean;
        float sc   = gamma[c] * rsqrtf(var + BN_EPS);
        float sh   = beta[c] - mean * sc;
        float v    = op[j] * sc + sh;
        res[j] = v > 0.f ? v : 0.f;
    }
    float4 xv = *(const float4*)&x[(size_t)idx * 4];
    res[0] += xv.x; res[1] += xv.y; res[2] += xv.z; res[3] += xv.w;
    float4 w1 = *(const float4*)&Wc[c4];
    float4 w2 = *(const float4*)&Wc[128 + c4];
    float a1 = res[0] * w1.x + res[1] * w1.y + res[2] * w1.z + res[3] * w1.w;
    float a2 = res[0] * w2.x + res[1] * w2.y + res[2] * w2.z + res[3] * w2.w;
    #pragma unroll
    for (int off = 1; off < 32; off <<= 1) {
        a1 += __shfl_xor(a1, off);
        a2 += __shfl_xor(a2, off);
    }
    if ((idx & 31) == 0) {
        int row = idx >> 5;
        s1[row] = a1;
        s2[row] = a2;
    }
}

// ---------------------------------------------------------------- edge predictor (scalar)
__global__ __launch_bounds__(256) void edge_pred_scalar(
    const float* __restrict__ s1, const float* __restrict__ s2,
    const int* __restrict__ ei, const float* __restrict__ bc,
    float* __restrict__ outp, int Ep)
{
    int e = blockIdx.x * 256 + threadIdx.x;
    if (e >= Ep) return;
    float v = s1[ei[e]] + s2[ei[Ep + e]] + bc[0];
    outp[e] = 1.f / (1.f + expf(-v));
}

// ---------------------------------------------------------------- launch
extern "C" void kernel_launch(void* const* d_in, const int* in_sizes, int n_in,
                              void* d_out, int out_size, void* d_ws, size_t ws_size,
                              hipStream_t stream) {
    const float* x        = (const float*)d_in[0];
    const int*   adj_row  = (const int*)  d_in[1];
    const int*   adj_col  = (const int*)  d_in[2];
    const float* adj_val  = (const float*)d_in[3];
    const int*   ei       = (const int*)  d_in[4];
    const float* W        = (const float*)d_in[5];
    const float* W_self   = (const float*)d_in[6];
    const float* b        = (const float*)d_in[7];
    const float* gamma    = (const float*)d_in[8];
    const float* beta     = (const float*)d_in[9];
    const float* Wc       = (const float*)d_in[10];
    const float* bc       = (const float*)d_in[11];
    float* outp = (float*)d_out;

    const int N  = in_sizes[0] / DD;    // 50000
    const int E  = in_sizes[1];         // 800000
    const int Ep = in_sizes[4] / 2;     // 500000
    const float invN = 1.f / (float)N;

    size_t nd = (size_t)N * DD;
    char* p = (char*)d_ws;
    unsigned short* support16 = (unsigned short*)p; p += nd * 2;
    float*          outbA     = (float*)p;          p += nd * 4;
    float*          outbB     = (float*)p;          p += nd * 4;
    unsigned short* Wt4       = (unsigned short*)p; p += 4 * 16384 * 2;
    float*          stats     = (float*)p;          p += 512 * 4;    // [L0 256][L1 256]
    int*            cnt       = (int*)p;            p += (size_t)N * 4;  // contiguous w/ stats
    int*            ovfc      = (int*)p;            p += 4;              // contiguous w/ cnt
    unsigned*       bucket    = (unsigned*)p;       p += (size_t)N * CAP * 4;
    int2*           ovf       = (int2*)p;           p += (size_t)OVF_MAX * 8;
    float*          s1        = (float*)p;          p += (size_t)N * 4;
    float*          s2        = (float*)p;          p += (size_t)N * 4;
    float*          partials  = (float*)p;          p += (size_t)SPMM_BLOCKS * 256 * 4;

    const int rpp = (N + 7) / 8;
    const int ngroups = (N + 7) / 8;
    const int nz = 512 + N + 1;             // stats + cnt + ovfc (contiguous)

    prep_zero<<<32 + (nz + 255) / 256, 256, 0, stream>>>(W, W_self, Wt4, (int*)stats, nz);
    scatter_bucket<<<256, 1024, 0, stream>>>(
        adj_row, adj_col, adj_val, cnt, bucket, ovfc, ovf, E, rpp);

    const int gemm_grid  = (N + 63) / 64;
    const int score_grid = (N * 32 + 255) / 256;

    // ---- layer 0 ----
    gemm_mfma<<<gemm_grid, 256, 0, stream>>>(
        x, Wt4 + 0 * 16384, Wt4 + 1 * 16384, b,
        nullptr, nullptr, nullptr, invN, 0,
        support16, outbA, N);
    spmm_stats<<<SPMM_BLOCKS, 256, 0, stream>>>(
        cnt, bucket, ovfc, ovf, support16, outbA, partials, ngroups, N);
    reduce_stats<<<32, 256, 0, stream>>>(partials, stats, SPMM_BLOCKS);

    // ---- layer 1 (BN of layer-0 fused into A staging) ----
    gemm_mfma<<<gemm_grid, 256, 0, stream>>>(
        outbA, Wt4 + 2 * 16384, Wt4 + 3 * 16384, b + DD,
        stats, gamma, beta, invN, 1,
        support16, outbB, N);
    spmm_stats<<<SPMM_BLOCKS, 256, 0, stream>>>(
        cnt, bucket, ovfc, ovf, support16, outbB, partials, ngroups, N);
    reduce_stats<<<32, 256, 0, stream>>>(partials, stats + 256, SPMM_BLOCKS);

    // ---- final BN + residual + factorized predictor ----
    score_kernel<<<score_grid, 256, 0, stream>>>(
        outbB, stats + 256, gamma + DD, beta + DD, x, Wc, s1, s2, invN, N);
    edge_pred_scalar<<<(Ep + 255) / 256, 256, 0, stream>>>(s1, s2, ei, bc, outp, Ep);
}

// Round 12
// 308.260 us; speedup vs baseline: 1.3824x; 1.0797x over previous
//
#include <hip/hip_runtime.h>
#include <hip/hip_bf16.h>
#include <hip/hip_fp16.h>

#define DD 128
#define BN_EPS 1e-5f
#define SPMM_BLOCKS 2048
#define SCAT_BLOCKS 2048     // 256 slices x 8 partitions
#define CAP 32               // bucket slots/row; P(Poisson(16)>32)~3e-5, ovf handles rest
#define OVF_MAX 8192

typedef __attribute__((ext_vector_type(8))) short bf16x8;
typedef __attribute__((ext_vector_type(4))) float f32x4;

static __device__ __forceinline__ unsigned short f2bf(float f) {
    __hip_bfloat16 h = __float2bfloat16(f);   // RNE
    return *reinterpret_cast<unsigned short*>(&h);
}
static __device__ __forceinline__ float bf2f(unsigned short u) {
    return __uint_as_float(((unsigned)u) << 16);
}
static __device__ __forceinline__ unsigned pack_rec(int col, float val) {
    __half h = __float2half(val);
    unsigned hb = *reinterpret_cast<unsigned short*>(&h);
    return (unsigned)col | (hb << 16);
}
static __device__ __forceinline__ float rec_val(unsigned rec) {
    unsigned short hb = (unsigned short)(rec >> 16);
    __half h = *reinterpret_cast<__half*>(&hb);
    return __half2float(h);
}

// ---------------------------------------------------------------- prep + zero (fused)
__global__ __launch_bounds__(256) void prep_zero(
    const float* __restrict__ W, const float* __restrict__ Wself,
    unsigned short* __restrict__ Wt4, int* __restrict__ zp, int nz)
{
    if (blockIdx.x < 32) {
        int mat   = blockIdx.x >> 3;       // 0:L0 W, 1:L0 Wself, 2:L1 W, 3:L1 Wself
        int chunk = blockIdx.x & 7;
        int layer = mat >> 1;
        const float* src = (mat & 1) ? (Wself + layer * 16384) : (W + layer * 16384);
        unsigned short* dst = Wt4 + (size_t)mat * 16384;
        int base = chunk * 2048 + threadIdx.x * 4;
        #pragma unroll
        for (int rep = 0; rep < 2; rep++) {
            int i = base + rep * 1024;          // i = k*128 + n
            float4 v = *(const float4*)&src[i];
            int k = i >> 7, n = i & 127;
            dst[(n + 0) * 128 + k] = f2bf(v.x);
            dst[(n + 1) * 128 + k] = f2bf(v.y);
            dst[(n + 2) * 128 + k] = f2bf(v.z);
            dst[(n + 3) * 128 + k] = f2bf(v.w);
        }
    } else {
        int i = (blockIdx.x - 32) * 256 + threadIdx.x;
        if (i < nz) zp[i] = 0;
    }
}

// ---------------------------------------------------------------- scatter body (device)
static __device__ __forceinline__ void scatter_body(
    int j, int nsl, int p,
    const int* __restrict__ arow, const int* __restrict__ acol,
    const float* __restrict__ aval, int* __restrict__ cnt,
    unsigned* __restrict__ bucket, int* __restrict__ ovfc,
    int2* __restrict__ ovf, int E, int rpp, int tstride)
{
    const int slice = j >> 3;
    const int e0 = (int)((long long)E * slice / nsl);
    const int e1 = (int)((long long)E * (slice + 1) / nsl);
    for (int e = e0 + threadIdx.x; e < e1; e += tstride) {
        int r = arow[e];
        if (r / rpp == p) {
            int pos = atomicAdd(&cnt[r], 1);
            unsigned rec = pack_rec(acol[e], aval[e]);
            if (pos < CAP) {
                bucket[(size_t)r * CAP + pos] = rec;
            } else {
                int oi = atomicAdd(ovfc, 1);
                if (oi < OVF_MAX) ovf[oi] = make_int2(r, (int)rec);
            }
        }
    }
}

// ---------------------------------------------------------------- gemm L0 + scatter (fused grid)
// blocks [0, gemm_grid): support = bf16(x@W0), outb = x@Wself0 + b0
// blocks [gemm_grid, ..): bucket scatter (latency-bound, overlaps MFMA blocks)
__global__ __launch_bounds__(256) void gemm_l0_scatter(
    const float* __restrict__ A,
    const unsigned short* __restrict__ Wt, const unsigned short* __restrict__ Wst,
    const float* __restrict__ bias,
    unsigned short* __restrict__ support, float* __restrict__ outb, int N, int gemm_grid,
    const int* __restrict__ arow, const int* __restrict__ acol,
    const float* __restrict__ aval, int* __restrict__ cnt,
    unsigned* __restrict__ bucket, int* __restrict__ ovfc,
    int2* __restrict__ ovf, int E, int rpp)
{
    if (blockIdx.x >= gemm_grid) {
        int j   = blockIdx.x - gemm_grid;
        int nsl = (gridDim.x - gemm_grid) >> 3;
        int p   = blockIdx.x & 7;           // global idx -> XCD-aligned partition
        scatter_body(j, nsl, p, arow, acol, aval, cnt, bucket, ovfc, ovf, E, rpp, 256);
        return;
    }

    const int wave = threadIdx.x >> 6;
    const int lane = threadIdx.x & 63;
    const int m    = lane & 15;
    const int quad = lane >> 4;
    const int row0 = blockIdx.x * 64 + wave * 16;

    int ar = row0 + m; if (ar > N - 1) ar = N - 1;
    const float* Ar = A + (size_t)ar * 128;
    bf16x8 af[4];
    #pragma unroll
    for (int ch = 0; ch < 4; ch++) {
        int k0 = ch * 32 + quad * 8;
        float4 u = *(const float4*)&Ar[k0];
        float4 v = *(const float4*)&Ar[k0 + 4];
        float vals[8] = {u.x, u.y, u.z, u.w, v.x, v.y, v.z, v.w};
        #pragma unroll
        for (int jj = 0; jj < 8; jj++) af[ch][jj] = (short)f2bf(vals[jj]);
    }

    f32x4 acc1[8], acc2[8];
    #pragma unroll
    for (int nt = 0; nt < 8; nt++) { acc1[nt] = (f32x4)(0.f); acc2[nt] = (f32x4)(0.f); }

    #pragma unroll
    for (int nt = 0; nt < 8; nt++) {
        const bf16x8* B1 = (const bf16x8*)(Wt  + ((size_t)(nt * 16 + m)) * 128 + quad * 8);
        const bf16x8* B2 = (const bf16x8*)(Wst + ((size_t)(nt * 16 + m)) * 128 + quad * 8);
        acc1[nt] = __builtin_amdgcn_mfma_f32_16x16x32_bf16(af[0], B1[0],  acc1[nt], 0, 0, 0);
        acc2[nt] = __builtin_amdgcn_mfma_f32_16x16x32_bf16(af[0], B2[0],  acc2[nt], 0, 0, 0);
        acc1[nt] = __builtin_amdgcn_mfma_f32_16x16x32_bf16(af[1], B1[4],  acc1[nt], 0, 0, 0);
        acc2[nt] = __builtin_amdgcn_mfma_f32_16x16x32_bf16(af[1], B2[4],  acc2[nt], 0, 0, 0);
        acc1[nt] = __builtin_amdgcn_mfma_f32_16x16x32_bf16(af[2], B1[8],  acc1[nt], 0, 0, 0);
        acc2[nt] = __builtin_amdgcn_mfma_f32_16x16x32_bf16(af[2], B2[8],  acc2[nt], 0, 0, 0);
        acc1[nt] = __builtin_amdgcn_mfma_f32_16x16x32_bf16(af[3], B1[12], acc1[nt], 0, 0, 0);
        acc2[nt] = __builtin_amdgcn_mfma_f32_16x16x32_bf16(af[3], B2[12], acc2[nt], 0, 0, 0);
    }

    float bv[8];
    #pragma unroll
    for (int nt = 0; nt < 8; nt++) bv[nt] = bias[nt * 16 + m];

    #pragma unroll
    for (int r = 0; r < 4; r++) {
        int orow = row0 + quad * 4 + r;
        if (orow < N) {
            size_t base = (size_t)orow * 128 + m;
            #pragma unroll
            for (int nt = 0; nt < 8; nt++) {
                support[base + nt * 16] = f2bf(acc1[nt][r]);
                outb[base + nt * 16]    = acc2[nt][r] + bv[nt];
            }
        }
    }
}

// ---------------------------------------------------------------- MFMA GEMM layer 1 (BN fused on A)
__global__ __launch_bounds__(256) void gemm_mfma_bn(
    const float* __restrict__ A,
    const unsigned short* __restrict__ Wt, const unsigned short* __restrict__ Wst,
    const float* __restrict__ bias,
    const float* __restrict__ stats, const float* __restrict__ gamma,
    const float* __restrict__ beta, float invN,
    unsigned short* __restrict__ support, float* __restrict__ outb, int N)
{
    __shared__ float ssc[128], ssh[128];
    if (threadIdx.x < 128) {
        int c = threadIdx.x;
        float mean = stats[c] * invN;
        float var  = stats[128 + c] * invN - mean * mean;
        float sc   = gamma[c] * rsqrtf(var + BN_EPS);
        ssc[c] = sc;
        ssh[c] = beta[c] - mean * sc;
    }
    __syncthreads();

    const int wave = threadIdx.x >> 6;
    const int lane = threadIdx.x & 63;
    const int m    = lane & 15;
    const int quad = lane >> 4;
    const int row0 = blockIdx.x * 64 + wave * 16;

    int ar = row0 + m; if (ar > N - 1) ar = N - 1;
    const float* Ar = A + (size_t)ar * 128;
    bf16x8 af[4];
    #pragma unroll
    for (int ch = 0; ch < 4; ch++) {
        int k0 = ch * 32 + quad * 8;
        float4 u = *(const float4*)&Ar[k0];
        float4 v = *(const float4*)&Ar[k0 + 4];
        float vals[8] = {u.x, u.y, u.z, u.w, v.x, v.y, v.z, v.w};
        #pragma unroll
        for (int j = 0; j < 8; j++) {
            float val = vals[j] * ssc[k0 + j] + ssh[k0 + j];
            val = val > 0.f ? val : 0.f;
            af[ch][j] = (short)f2bf(val);
        }
    }

    f32x4 acc1[8], acc2[8];
    #pragma unroll
    for (int nt = 0; nt < 8; nt++) { acc1[nt] = (f32x4)(0.f); acc2[nt] = (f32x4)(0.f); }

    #pragma unroll
    for (int nt = 0; nt < 8; nt++) {
        const bf16x8* B1 = (const bf16x8*)(Wt  + ((size_t)(nt * 16 + m)) * 128 + quad * 8);
        const bf16x8* B2 = (const bf16x8*)(Wst + ((size_t)(nt * 16 + m)) * 128 + quad * 8);
        acc1[nt] = __builtin_amdgcn_mfma_f32_16x16x32_bf16(af[0], B1[0],  acc1[nt], 0, 0, 0);
        acc2[nt] = __builtin_amdgcn_mfma_f32_16x16x32_bf16(af[0], B2[0],  acc2[nt], 0, 0, 0);
        acc1[nt] = __builtin_amdgcn_mfma_f32_16x16x32_bf16(af[1], B1[4],  acc1[nt], 0, 0, 0);
        acc2[nt] = __builtin_amdgcn_mfma_f32_16x16x32_bf16(af[1], B2[4],  acc2[nt], 0, 0, 0);
        acc1[nt] = __builtin_amdgcn_mfma_f32_16x16x32_bf16(af[2], B1[8],  acc1[nt], 0, 0, 0);
        acc2[nt] = __builtin_amdgcn_mfma_f32_16x16x32_bf16(af[2], B2[8],  acc2[nt], 0, 0, 0);
        acc1[nt] = __builtin_amdgcn_mfma_f32_16x16x32_bf16(af[3], B1[12], acc1[nt], 0, 0, 0);
        acc2[nt] = __builtin_amdgcn_mfma_f32_16x16x32_bf16(af[3], B2[12], acc2[nt], 0, 0, 0);
    }

    float bv[8];
    #pragma unroll
    for (int nt = 0; nt < 8; nt++) bv[nt] = bias[nt * 16 + m];

    #pragma unroll
    for (int r = 0; r < 4; r++) {
        int orow = row0 + quad * 4 + r;
        if (orow < N) {
            size_t base = (size_t)orow * 128 + m;
            #pragma unroll
            for (int nt = 0; nt < 8; nt++) {
                support[base + nt * 16] = f2bf(acc1[nt][r]);
                outb[base + nt * 16]    = acc2[nt][r] + bv[nt];
            }
        }
    }
}

// ---------------------------------------------------------------- SpMM (bucket) + fused BN stats
__global__ __launch_bounds__(256) void spmm_stats(
    const int* __restrict__ cnt, const unsigned* __restrict__ bucket,
    const int* __restrict__ ovfc, const int2* __restrict__ ovf,
    const unsigned short* __restrict__ sup, float* __restrict__ outb,
    float* __restrict__ partials, int ngroups, int N)
{
    const int r    = threadIdx.x & 31;   // column quad
    const int slot = threadIdx.x >> 5;   // row within group
    float s4[4] = {0.f, 0.f, 0.f, 0.f};
    float q4[4] = {0.f, 0.f, 0.f, 0.f};

    for (int g = blockIdx.x; g < ngroups; g += gridDim.x) {
        int row = g * 8 + slot;
        if (row >= N) continue;
        int nrec = cnt[row]; if (nrec > CAP) nrec = CAP;
        const unsigned* packed = bucket + (size_t)row * CAP;

        float4 acc = make_float4(0.f, 0.f, 0.f, 0.f);
        int e = 0;
        for (; e + 4 <= nrec; e += 4) {
            unsigned p0 = packed[e + 0];
            unsigned p1 = packed[e + 1];
            unsigned p2 = packed[e + 2];
            unsigned p3 = packed[e + 3];
            ushort4 s0 = *(const ushort4*)&sup[((size_t)(p0 & 0xFFFFu) << 7) + r * 4];
            ushort4 s1 = *(const ushort4*)&sup[((size_t)(p1 & 0xFFFFu) << 7) + r * 4];
            ushort4 s2 = *(const ushort4*)&sup[((size_t)(p2 & 0xFFFFu) << 7) + r * 4];
            ushort4 s3 = *(const ushort4*)&sup[((size_t)(p3 & 0xFFFFu) << 7) + r * 4];
            float v0 = rec_val(p0), v1 = rec_val(p1);
            float v2 = rec_val(p2), v3 = rec_val(p3);
            acc.x += v0 * bf2f(s0.x); acc.y += v0 * bf2f(s0.y);
            acc.z += v0 * bf2f(s0.z); acc.w += v0 * bf2f(s0.w);
            acc.x += v1 * bf2f(s1.x); acc.y += v1 * bf2f(s1.y);
            acc.z += v1 * bf2f(s1.z); acc.w += v1 * bf2f(s1.w);
            acc.x += v2 * bf2f(s2.x); acc.y += v2 * bf2f(s2.y);
            acc.z += v2 * bf2f(s2.z); acc.w += v2 * bf2f(s2.w);
            acc.x += v3 * bf2f(s3.x); acc.y += v3 * bf2f(s3.y);
            acc.z += v3 * bf2f(s3.z); acc.w += v3 * bf2f(s3.w);
        }
        for (; e < nrec; e++) {
            unsigned pr = packed[e];
            ushort4 sv = *(const ushort4*)&sup[((size_t)(pr & 0xFFFFu) << 7) + r * 4];
            float v = rec_val(pr);
            acc.x += v * bf2f(sv.x); acc.y += v * bf2f(sv.y);
            acc.z += v * bf2f(sv.z); acc.w += v * bf2f(sv.w);
        }

        // overflow records (rare; exactness safety net)
        int oc = *ovfc;
        if (oc > 0) {
            if (oc > OVF_MAX) oc = OVF_MAX;
            for (int i = 0; i < oc; i++) {
                int2 orec = ovf[i];
                if (orec.x == row) {
                    unsigned pr = (unsigned)orec.y;
                    ushort4 sv = *(const ushort4*)&sup[((size_t)(pr & 0xFFFFu) << 7) + r * 4];
                    float v = rec_val(pr);
                    acc.x += v * bf2f(sv.x); acc.y += v * bf2f(sv.y);
                    acc.z += v * bf2f(sv.z); acc.w += v * bf2f(sv.w);
                }
            }
        }

        float4* op = (float4*)&outb[((size_t)row << 7) + r * 4];
        float4 o = *op;
        o.x += acc.x; o.y += acc.y; o.z += acc.z; o.w += acc.w;
        *op = o;
        s4[0] += o.x; s4[1] += o.y; s4[2] += o.z; s4[3] += o.w;
        q4[0] += o.x * o.x; q4[1] += o.y * o.y; q4[2] += o.z * o.z; q4[3] += o.w * o.w;
    }

    __shared__ float red[8][128];
    #pragma unroll
    for (int j = 0; j < 4; j++) red[slot][r * 4 + j] = s4[j];
    __syncthreads();
    float ts = 0.f;
    if (threadIdx.x < 128) {
        #pragma unroll
        for (int j = 0; j < 8; j++) ts += red[j][threadIdx.x];
        partials[(size_t)blockIdx.x * 256 + threadIdx.x] = ts;   // non-atomic
    }
    __syncthreads();
    #pragma unroll
    for (int j = 0; j < 4; j++) red[slot][r * 4 + j] = q4[j];
    __syncthreads();
    if (threadIdx.x < 128) {
        float tq = 0.f;
        #pragma unroll
        for (int j = 0; j < 8; j++) tq += red[j][threadIdx.x];
        partials[(size_t)blockIdx.x * 256 + 128 + threadIdx.x] = tq;
    }
}

// ---------------------------------------------------------------- partials -> stats
__global__ __launch_bounds__(256) void reduce_stats(
    const float* __restrict__ partials, float* __restrict__ stats, int nblk)
{
    int g = blockIdx.x;
    int per = (nblk + gridDim.x - 1) / gridDim.x;
    int b0 = g * per, b1 = min(b0 + per, nblk);
    float a0 = 0.f;
    for (int b = b0; b < b1; b++) {
        a0 += partials[(size_t)b * 256 + threadIdx.x];
    }
    atomicAdd(&stats[threadIdx.x], a0);
}

// ---------------------------------------------------------------- final BN + residual + score
__global__ __launch_bounds__(256) void score_kernel(
    const float* __restrict__ outb, const float* __restrict__ stats,
    const float* __restrict__ gamma, const float* __restrict__ beta,
    const float* __restrict__ x, const float* __restrict__ Wc,
    float* __restrict__ s1, float* __restrict__ s2, float invN, int N)
{
    int idx = blockIdx.x * 256 + threadIdx.x;
    if (idx >= N * 32) return;
    int c4 = (idx & 31) * 4;
    float4 o = *(const float4*)&outb[(size_t)idx * 4];
    float res[4];
    const float* op = &o.x;
    #pragma unroll
    for (int j = 0; j < 4; j++) {
        int c = c4 + j;
        float mean = stats[c] * invN;
        float var  = stats[128 + c] * invN - mean * mean;
        float sc   = gamma[c] * rsqrtf(var + BN_EPS);
        float sh   = beta[c] - mean * sc;
        float v    = op[j] * sc + sh;
        res[j] = v > 0.f ? v : 0.f;
    }
    float4 xv = *(const float4*)&x[(size_t)idx * 4];
    res[0] += xv.x; res[1] += xv.y; res[2] += xv.z; res[3] += xv.w;
    float4 w1 = *(const float4*)&Wc[c4];
    float4 w2 = *(const float4*)&Wc[128 + c4];
    float a1 = res[0] * w1.x + res[1] * w1.y + res[2] * w1.z + res[3] * w1.w;
    float a2 = res[0] * w2.x + res[1] * w2.y + res[2] * w2.z + res[3] * w2.w;
    #pragma unroll
    for (int off = 1; off < 32; off <<= 1) {
        a1 += __shfl_xor(a1, off);
        a2 += __shfl_xor(a2, off);
    }
    if ((idx & 31) == 0) {
        int row = idx >> 5;
        s1[row] = a1;
        s2[row] = a2;
    }
}

// ---------------------------------------------------------------- edge predictor (scalar)
__global__ __launch_bounds__(256) void edge_pred_scalar(
    const float* __restrict__ s1, const float* __restrict__ s2,
    const int* __restrict__ ei, const float* __restrict__ bc,
    float* __restrict__ outp, int Ep)
{
    int e = blockIdx.x * 256 + threadIdx.x;
    if (e >= Ep) return;
    float v = s1[ei[e]] + s2[ei[Ep + e]] + bc[0];
    outp[e] = 1.f / (1.f + expf(-v));
}

// ---------------------------------------------------------------- launch
extern "C" void kernel_launch(void* const* d_in, const int* in_sizes, int n_in,
                              void* d_out, int out_size, void* d_ws, size_t ws_size,
                              hipStream_t stream) {
    const float* x        = (const float*)d_in[0];
    const int*   adj_row  = (const int*)  d_in[1];
    const int*   adj_col  = (const int*)  d_in[2];
    const float* adj_val  = (const float*)d_in[3];
    const int*   ei       = (const int*)  d_in[4];
    const float* W        = (const float*)d_in[5];
    const float* W_self   = (const float*)d_in[6];
    const float* b        = (const float*)d_in[7];
    const float* gamma    = (const float*)d_in[8];
    const float* beta     = (const float*)d_in[9];
    const float* Wc       = (const float*)d_in[10];
    const float* bc       = (const float*)d_in[11];
    float* outp = (float*)d_out;

    const int N  = in_sizes[0] / DD;    // 50000
    const int E  = in_sizes[1];         // 800000
    const int Ep = in_sizes[4] / 2;     // 500000
    const float invN = 1.f / (float)N;

    size_t nd = (size_t)N * DD;
    char* p = (char*)d_ws;
    unsigned short* support16 = (unsigned short*)p; p += nd * 2;
    float*          outbA     = (float*)p;          p += nd * 4;
    float*          outbB     = (float*)p;          p += nd * 4;
    unsigned short* Wt4       = (unsigned short*)p; p += 4 * 16384 * 2;
    float*          stats     = (float*)p;          p += 512 * 4;    // [L0 256][L1 256]
    int*            cnt       = (int*)p;            p += (size_t)N * 4;  // contiguous w/ stats
    int*            ovfc      = (int*)p;            p += 4;              // contiguous w/ cnt
    unsigned*       bucket    = (unsigned*)p;       p += (size_t)N * CAP * 4;
    int2*           ovf       = (int2*)p;           p += (size_t)OVF_MAX * 8;
    float*          s1        = (float*)p;          p += (size_t)N * 4;
    float*          s2        = (float*)p;          p += (size_t)N * 4;
    float*          partials  = (float*)p;          p += (size_t)SPMM_BLOCKS * 256 * 4;

    const int rpp = (N + 7) / 8;
    const int ngroups = (N + 7) / 8;
    const int nz = 512 + N + 1;             // stats + cnt + ovfc (contiguous)

    const int gemm_grid  = (N + 63) / 64;
    const int score_grid = (N * 32 + 255) / 256;

    prep_zero<<<32 + (nz + 255) / 256, 256, 0, stream>>>(W, W_self, Wt4, (int*)stats, nz);

    // ---- layer 0 GEMM + bucket scatter (fused grid; scatter overlaps MFMA) ----
    gemm_l0_scatter<<<gemm_grid + SCAT_BLOCKS, 256, 0, stream>>>(
        x, Wt4 + 0 * 16384, Wt4 + 1 * 16384, b,
        support16, outbA, N, gemm_grid,
        adj_row, adj_col, adj_val, cnt, bucket, ovfc, ovf, E, rpp);
    spmm_stats<<<SPMM_BLOCKS, 256, 0, stream>>>(
        cnt, bucket, ovfc, ovf, support16, outbA, partials, ngroups, N);
    reduce_stats<<<32, 256, 0, stream>>>(partials, stats, SPMM_BLOCKS);

    // ---- layer 1 (BN of layer-0 fused into A staging) ----
    gemm_mfma_bn<<<gemm_grid, 256, 0, stream>>>(
        outbA, Wt4 + 2 * 16384, Wt4 + 3 * 16384, b + DD,
        stats, gamma, beta, invN,
        support16, outbB, N);
    spmm_stats<<<SPMM_BLOCKS, 256, 0, stream>>>(
        cnt, bucket, ovfc, ovf, support16, outbB, partials, ngroups, N);
    reduce_stats<<<32, 256, 0, stream>>>(partials, stats + 256, SPMM_BLOCKS);

    // ---- final BN + residual + factorized predictor ----
    score_kernel<<<score_grid, 256, 0, stream>>>(
        outbB, stats + 256, gamma + DD, beta + DD, x, Wc, s1, s2, invN, N);
    edge_pred_scalar<<<(Ep + 255) / 256, 256, 0, stream>>>(s1, s2, ei, bc, outp, Ep);
}